// Round 9
// baseline (1007.891 us; speedup 1.0000x reference)
//
#include <hip/hip_runtime.h>
#include <hip/hip_bf16.h>
#include <math.h>

static constexpr int kNC = 10;
static constexpr int kNLab = 256;
static constexpr int kMaxIter = 30;

using short8 = __attribute__((ext_vector_type(8))) short;
using f32x4  = __attribute__((ext_vector_type(4))) float;

__device__ __forceinline__ unsigned short f2bf(float f) {
  unsigned int u = __float_as_uint(f);
  u += 0x7FFFu + ((u >> 16) & 1u);   // RNE
  return (unsigned short)(u >> 16);
}
__device__ __forceinline__ float bf2f(unsigned short u) {
  return __uint_as_float(((unsigned int)u) << 16);
}

// ---------------- NCHW fp32 -> NHWC bf16 transpose (per (n,h) row) ----------------
template <int C, int S>
__global__ __launch_bounds__(256) void xpack_kernel(const float* __restrict__ x,
                                                    unsigned short* __restrict__ xp) {
  __shared__ float t[C][S + 1];
  const int n = blockIdx.x / S, h = blockIdx.x % S;
  const float* src = x + (size_t)n * C * S * S;
  for (int e = threadIdx.x; e < C * S; e += 256) {
    int c = e / S, w = e % S;
    t[c][w] = src[((size_t)c * S + h) * S + w];
  }
  __syncthreads();
  unsigned short* dst = xp + ((size_t)(n * S + h) * S) * C;
  for (int e = threadIdx.x; e < C * S; e += 256) {
    int w = e / C, c = e % C;
    dst[(size_t)w * C + c] = f2bf(t[c][w]);
  }
}

// ---------------- all-branch weight pack into MFMA A-fragment order bf16 ----------
// per-branch layout: [tap][cik][co16][lane][8]; co=co16*16+(l&15), ci=cik*32+(l>>4)*8+e
__global__ void wpack_all(const float* __restrict__ w0, const float* __restrict__ w1,
                          const float* __restrict__ w2, const float* __restrict__ w3,
                          unsigned short* __restrict__ wpk) {
  int idx = blockIdx.x * 256 + threadIdx.x;
  if (idx >= 3133440) return;
  const float* w; int C, off;
  if (idx < 36864)        { w = w0; C = 64;  off = 0; }
  else if (idx < 184320)  { w = w1; C = 128; off = 36864; }
  else if (idx < 774144)  { w = w2; C = 256; off = 184320; }
  else                    { w = w3; C = 512; off = 774144; }
  int e = idx - off;
  int CO16T = C / 16, CIK = C / 32;
  int e8 = e & 7, l = (e >> 3) & 63;
  int rest = e >> 9;
  int co16 = rest % CO16T;
  int rest2 = rest / CO16T;
  int cik = rest2 % CIK, tap = rest2 / CIK;
  int co = co16 * 16 + (l & 15);
  int ci = cik * 32 + (l >> 4) * 8 + e8;
  wpk[idx] = f2bf(w[((size_t)co * C + ci) * 9 + tap]);
}

// ---------------- MFMA implicit-GEMM 3x3 SAME conv ----------------
// block: WV waves; px-tile PXB = NI*NR*S; per-wave BF 16-px fragments; 64 co per block.
// MODE 0: store y(NHWC bf16)+stats partials; 1: stats only; 2: fused BN+relu+pool partials
template <int C, int S, int NI, int NR, int WV, int BF, int MODE>
__global__ __launch_bounds__(WV * 64)
void conv_mfma(const unsigned short* __restrict__ xp, const unsigned short* __restrict__ wpk,
               const float* __restrict__ bias, unsigned short* __restrict__ y,
               float* __restrict__ psum, float* __restrict__ psq, int npart, int partBase,
               const float* __restrict__ scale, const float* __restrict__ shift,
               float* __restrict__ pp, int pxGlobalBase) {
  constexpr int SS = S * S;
  constexpr int PXB = NI * NR * S;
  constexpr int TPB = WV * 64;
  constexpr int HR = NR + 2, HC = S + 2;
  constexpr int CIK = C / 32, CO16T = C / 16;
  constexpr int UNITS = NI * HR * HC * 4;
  constexpr int NU = (UNITS + TPB - 1) / TPB;
  static_assert(WV * BF * 16 == PXB, "wave px mismatch");
  static_assert(MODE != 2 || BF == 4, "MODE2 assumes 64px/wave");
  __shared__ __align__(16) char xs[NI * HR * HC * 80];

  const int tid = threadIdx.x;
  const int wv = tid >> 6, l = tid & 63, l15 = l & 15, l4 = l >> 4;
  const int coblk = blockIdx.y;
  const int co_base = coblk * 64;
  const int pxb = blockIdx.x * PXB;
  const int n_t = pxb / SS;
  const int r0 = (pxb % SS) / S;

  int pxoff[BF];
#pragma unroll
  for (int bf = 0; bf < BF; ++bf) {
    int pxloc = wv * (BF * 16) + bf * 16 + l15;
    int ii = pxloc / (NR * S);
    int rr = (pxloc % (NR * S)) / S;
    int cc = pxloc % S;
    pxoff[bf] = ((ii * HR + rr) * HC + cc) * 80 + l4 * 16;
  }

  f32x4 acc[4][BF];
#pragma unroll
  for (int a = 0; a < 4; ++a)
#pragma unroll
    for (int b = 0; b < BF; ++b) acc[a][b] = (f32x4){0.f, 0.f, 0.f, 0.f};

  uint4 vreg[NU];
  auto loadU = [&](int cik) {
#pragma unroll
    for (int k = 0; k < NU; ++k) {
      int u = tid + k * TPB;
      uint4 v = {0u, 0u, 0u, 0u};
      if (u < UNITS) {
        int k16 = u & 3;
        int t = u >> 2;
        int hc = t % HC;
        int t2 = t / HC;
        int hr = t2 % HR;
        int ii = t2 / HR;
        int row = r0 + hr - 1, col = hc - 1;
        if (row >= 0 && row < S && col >= 0 && col < S)
          v = *(const uint4*)(xp + ((size_t)((n_t + ii) * S + row) * S + col) * C + cik * 32 + k16 * 8);
      }
      vreg[k] = v;
    }
  };

  loadU(0);
  for (int cik = 0; cik < CIK; ++cik) {
    __syncthreads();     // previous readers done
#pragma unroll
    for (int k = 0; k < NU; ++k) {
      int u = tid + k * TPB;
      if (u < UNITS) *(uint4*)(xs + (u >> 2) * 80 + (u & 3) * 16) = vreg[k];
    }
    __syncthreads();
    if (cik + 1 < CIK) loadU(cik + 1);   // in flight during MFMA phase
#pragma unroll
    for (int tap = 0; tap < 9; ++tap) {
      const int tapoff = ((tap / 3) * HC + (tap % 3)) * 80;
      short8 wf[4], xf[BF];
#pragma unroll
      for (int af = 0; af < 4; ++af)
        wf[af] = *(const short8*)(wpk + ((size_t)((tap * CIK + cik) * CO16T + coblk * 4 + af) * 64 + l) * 8);
#pragma unroll
      for (int bf = 0; bf < BF; ++bf)
        xf[bf] = *(const short8*)(xs + pxoff[bf] + tapoff);
#pragma unroll
      for (int af = 0; af < 4; ++af)
#pragma unroll
        for (int bf = 0; bf < BF; ++bf)
          acc[af][bf] = __builtin_amdgcn_mfma_f32_16x16x32_bf16(wf[af], xf[bf], acc[af][bf], 0, 0, 0);
    }
  }

  // ---------------- epilogue ----------------
#pragma unroll
  for (int af = 0; af < 4; ++af) {
    const int co0 = co_base + af * 16 + l4 * 4;
    float4 bv = *(const float4*)(bias + co0);
    float s[4] = {0.f, 0.f, 0.f, 0.f}, q[4] = {0.f, 0.f, 0.f, 0.f};
    float4 sc4, sh4;
    if (MODE == 2) {
      sc4 = *(const float4*)(scale + co0);
      sh4 = *(const float4*)(shift + co0);
    }
#pragma unroll
    for (int bf = 0; bf < BF; ++bf) {
      float o[4];
#pragma unroll
      for (int r = 0; r < 4; ++r) o[r] = acc[af][bf][r] + ((const float*)&bv)[r];
      if (MODE == 0) {
        ushort4 pk;
        pk.x = f2bf(o[0]); pk.y = f2bf(o[1]); pk.z = f2bf(o[2]); pk.w = f2bf(o[3]);
        size_t px = (size_t)(pxb + wv * (BF * 16) + bf * 16 + l15);
        *(ushort4*)(y + px * C + co0) = pk;
      }
      if (MODE == 2) {
#pragma unroll
        for (int r = 0; r < 4; ++r)
          s[r] += fmaxf(fmaf(((const float*)&sc4)[r], o[r], ((const float*)&sh4)[r]), 0.f);
      } else {
#pragma unroll
        for (int r = 0; r < 4; ++r) { s[r] += o[r]; q[r] += o[r] * o[r]; }
      }
    }
#pragma unroll
    for (int m = 1; m < 16; m <<= 1) {
#pragma unroll
      for (int r = 0; r < 4; ++r) {
        s[r] += __shfl_xor(s[r], m);
        if (MODE != 2) q[r] += __shfl_xor(q[r], m);
      }
    }
    if (l15 == 0) {
      if (MODE == 2) {
        int n = (pxGlobalBase + pxb) / SS;
        int qw = ((pxGlobalBase + pxb) % SS) / 64 + wv;
#pragma unroll
        for (int r = 0; r < 4; ++r)
          pp[((size_t)(n * C + co0 + r)) * 16 + qw] = s[r];
      } else {
        int part = partBase + blockIdx.x * WV + wv;
#pragma unroll
        for (int r = 0; r < 4; ++r) {
          psum[(size_t)(co0 + r) * npart + part] = s[r];
          psq[(size_t)(co0 + r) * npart + part] = q[r];
        }
      }
    }
  }
}

// ---------------- BN stats finalize (deterministic tree) ----------------
__global__ __launch_bounds__(256)
void stats2_kernel(const float* __restrict__ psum, const float* __restrict__ psq,
                   const float* __restrict__ g, const float* __restrict__ bb,
                   float* __restrict__ scale, float* __restrict__ shift,
                   int npart, float invN) {
  int c = blockIdx.x;
  __shared__ float rs[256], rq[256];
  float s = 0.f, q = 0.f;
  for (int p = threadIdx.x; p < npart; p += 256) {
    s += psum[(size_t)c * npart + p];
    q += psq[(size_t)c * npart + p];
  }
  rs[threadIdx.x] = s; rq[threadIdx.x] = q;
  __syncthreads();
  for (int st = 128; st; st >>= 1) {
    if (threadIdx.x < st) { rs[threadIdx.x] += rs[threadIdx.x + st]; rq[threadIdx.x] += rq[threadIdx.x + st]; }
    __syncthreads();
  }
  if (threadIdx.x == 0) {
    float m = rs[0] * invN;
    float v = rq[0] * invN - m * m;
    float sc = g[c] / sqrtf(v + 1e-5f);
    scale[c] = sc;
    shift[c] = bb[c] - m * sc;
  }
}

// ---------------- fused relu(bn(y NHWC)) spatial mean + linear -> oc ----------------
template <int C, int S>
__global__ __launch_bounds__(256)
void pool_lin(const unsigned short* __restrict__ y, const float* __restrict__ scale,
              const float* __restrict__ shift, const float* __restrict__ lw,
              const float* __restrict__ lb, float* __restrict__ oc, int brOff) {
  constexpr int SS = S * S;
  int n = blockIdx.x;
  const unsigned short* yr = y + (size_t)n * SS * C;
  __shared__ float pl[C];
  if (C >= 256) {
    for (int co = threadIdx.x; co < C; co += 256) {
      float sc = scale[co], sh = shift[co], s = 0.f;
      for (int p = 0; p < SS; ++p) s += fmaxf(fmaf(sc, bf2f(yr[(size_t)p * C + co]), sh), 0.f);
      pl[co] = s * (1.f / SS);
    }
  } else {
    constexpr int G = 256 / C;
    int co = threadIdx.x % C;
    int sl = threadIdx.x / C;
    float sc = scale[co], sh = shift[co], s = 0.f;
    for (int p = sl; p < SS; p += G) s += fmaxf(fmaf(sc, bf2f(yr[(size_t)p * C + co]), sh), 0.f);
    __shared__ float red[256];
    red[threadIdx.x] = s;
    __syncthreads();
    if (threadIdx.x < C) {
      float t = 0.f;
      for (int gg = 0; gg < G; ++gg) t += red[gg * C + co];
      pl[co] = t * (1.f / SS);
    }
  }
  __syncthreads();
  if (threadIdx.x < 128) {
    int j = threadIdx.x;
    const float* wr = lw + (size_t)j * C;
    float s = 0.f;
    for (int t = 0; t < C; ++t) s = fmaf(pl[t], wr[t], s);
    s += lb[j];
    oc[n * 512 + brOff + j] = fmaxf(s, 0.f);
  }
}

// ---------------- branch-0 fallback fused-pool finalize ----------------
__global__ void poolfin_kernel(const float* __restrict__ pp, float* __restrict__ pooled) {
  int i = blockIdx.x * 256 + threadIdx.x;
  if (i >= 512 * 64) return;
  float s = 0.f;
  for (int qn = 0; qn < 16; ++qn) s += pp[(size_t)i * 16 + qn];
  pooled[i] = s * (1.f / 1024.f);
}

// ---------------- relu(pooled @ lw.T + lb) -> oc[n][512] at brOff (fallback) -------
__global__ void lin_kernel(const float* __restrict__ pooled, const float* __restrict__ lw,
                           const float* __restrict__ lb, float* __restrict__ oc,
                           int C, int brOff) {
  int idx = blockIdx.x * 256 + threadIdx.x;
  if (idx >= 512 * 128) return;
  int j = idx & 127, n = idx >> 7;
  const float4* pr = (const float4*)(pooled + (size_t)n * C);
  const float4* wr = (const float4*)(lw + (size_t)j * C);
  float s = 0.f;
  for (int t = 0; t < C / 4; ++t) {
    float4 a = pr[t], b = wr[t];
    s += a.x * b.x + a.y * b.y + a.z * b.z + a.w * b.w;
  }
  s += lb[j];
  oc[n * 512 + brOff + j] = fmaxf(s, 0.f);
}

__global__ void ypred_kernel(const float* __restrict__ oc, const float* __restrict__ fw,
                             const float* __restrict__ fb, float* __restrict__ out) {
  int wv = threadIdx.x >> 6, l = threadIdx.x & 63;
  int n = blockIdx.x * 4 + wv;
  float s = 0.f;
  for (int k = l; k < 512; k += 64) s += oc[n * 512 + k] * fw[k];
#pragma unroll
  for (int m = 32; m; m >>= 1) s += __shfl_down(s, m);
  if (l == 0) out[n] = s + fb[0];
}

// ---------------- GTG graph build ----------------
__global__ void sqnorm_kernel(const float* __restrict__ E, float* __restrict__ sq) {
  int wv = threadIdx.x >> 6, l = threadIdx.x & 63;
  int n = blockIdx.x * 4 + wv;
  const float* row = E + (size_t)n * 512;
  float s = 0.f;
  for (int k = l; k < 512; k += 64) { float v = row[k]; s += v * v; }
#pragma unroll
  for (int m = 32; m; m >>= 1) s += __shfl_down(s, m);
  if (l == 0) sq[n] = s;
}

__global__ __launch_bounds__(256) void a0_kernel(const float* __restrict__ E,
                                                 const float* __restrict__ sq,
                                                 float* __restrict__ A0) {
  int bi = blockIdx.x / 32, bj = blockIdx.x % 32;
  int ti = threadIdx.x % 16, tj = threadIdx.x / 16;
  __shared__ float Ei[16][68], Ej[16][68];
  float acc = 0.f;
  for (int k0 = 0; k0 < 512; k0 += 64) {
    for (int e = threadIdx.x; e < 1024; e += 256) {
      int rr = e >> 6, cc = e & 63;
      Ei[rr][cc] = E[(size_t)(bi * 16 + rr) * 512 + k0 + cc];
      Ej[rr][cc] = E[(size_t)(bj * 16 + rr) * 512 + k0 + cc];
    }
    __syncthreads();
#pragma unroll 16
    for (int kk = 0; kk < 64; ++kk) acc = fmaf(Ei[tj][kk], Ej[ti][kk], acc);
    __syncthreads();
  }
  int i = bi * 16 + tj, j = bj * 16 + ti;
  float d2 = fmaxf(sq[i] + sq[j] - 2.f * acc, 0.f);
  A0[(size_t)i * 512 + j] = fminf(fmaxf(sqrtf(d2), 0.1f), 1.0f);
}

__global__ void seventh_kernel(const float* __restrict__ A0, int* __restrict__ idx7) {
  int i = blockIdx.x * 256 + threadIdx.x;
  if (i >= 512) return;
  float v[7]; int ix[7];
#pragma unroll
  for (int t = 0; t < 7; ++t) { v[t] = 3.4e38f; ix[t] = 0; }
  const float* row = A0 + (size_t)i * 512;
  for (int j = 0; j < 512; ++j) {
    float a = row[j];
    if (a < v[6]) {
      int pos = 6;
      while (pos > 0 && a < v[pos - 1]) { v[pos] = v[pos - 1]; ix[pos] = ix[pos - 1]; --pos; }
      v[pos] = a; ix[pos] = j;
    }
  }
  idx7[i] = ix[6];
}

__global__ void sig_kernel(const float* __restrict__ E, const int* __restrict__ idx7,
                           float* __restrict__ sig) {
  int wv = threadIdx.x >> 6, l = threadIdx.x & 63;
  int n = blockIdx.x * 4 + wv;
  const float* r1 = E + (size_t)n * 512;
  const float* r2 = E + (size_t)idx7[n] * 512;
  float s = 0.f;
  for (int k = l; k < 512; k += 64) { float d = r1[k] - r2[k]; s += d * d; }
#pragma unroll
  for (int m = 32; m; m >>= 1) s += __shfl_down(s, m);
  if (l == 0) sig[n] = fminf(fmaxf(sqrtf(s), 0.1f), 1.0f);
}

__global__ void aexp_kernel(const float* __restrict__ A0, const float* __restrict__ sig,
                            float* __restrict__ A, float* __restrict__ part) {
  int t = blockIdx.x * 256 + threadIdx.x;
  int base = t * 4;
  int i = base >> 9, j0 = base & 511;
  float si = sig[i];
  float4 a = *(const float4*)(A0 + base);
  float4 o;
  o.x = fminf(fmaxf(expf(-a.x * a.x / (si * sig[j0 + 0])), 0.f), 1.f);
  o.y = fminf(fmaxf(expf(-a.y * a.y / (si * sig[j0 + 1])), 0.f), 1.f);
  o.z = fminf(fmaxf(expf(-a.z * a.z / (si * sig[j0 + 2])), 0.f), 1.f);
  o.w = fminf(fmaxf(expf(-a.w * a.w / (si * sig[j0 + 3])), 0.f), 1.f);
  *(float4*)(A + base) = o;
  float lsum = o.x + o.y + o.z + o.w;
#pragma unroll
  for (int m = 32; m; m >>= 1) lsum += __shfl_down(lsum, m);
  __shared__ float sred[4];
  if ((threadIdx.x & 63) == 0) sred[threadIdx.x >> 6] = lsum;
  __syncthreads();
  if (threadIdx.x == 0) part[blockIdx.x] = sred[0] + sred[1] + sred[2] + sred[3];
}

__global__ void meanred_kernel(const float* __restrict__ part, float* __restrict__ meanA) {
  if (threadIdx.x == 0 && blockIdx.x == 0) {
    float s = 0.f;
    for (int p = 0; p < 256; ++p) s += part[p];
    meanA[0] = s * (1.0f / 262144.0f);
  }
}

__global__ void thresh_kernel(float* __restrict__ A, const float* __restrict__ meanA) {
  int t = blockIdx.x * 256 + threadIdx.x;
  int base = t * 4;
  int i = base >> 9, j0 = base & 511;
  float m = meanA[0];
  float4 v = *(const float4*)(A + base);
  v.x = v.x > m ? 1.f : v.x;
  v.y = v.y > m ? 1.f : v.y;
  v.z = v.z > m ? 1.f : v.z;
  v.w = v.w > m ? 1.f : v.w;
  if (i < kNLab && j0 < kNLab) {
    v.x = 1.f - v.x; v.y = 1.f - v.y; v.z = 1.f - v.z; v.w = 1.f - v.w;
  }
  *(float4*)(A + base) = v;
}

// ---------------- replicator: SINGLE block, no grid barrier ----------------
// Labeled rows stay EXACTLY one-hot (xn = e_c * ax -> renorm = e_c in IEEE, ax[c]>0),
// entropy/diff exactly 0 -- identical to reference. Only 256 unlabeled rows iterate:
// ax = L + A_uu @ Xu, L[i][c] = sum_{j<256,lab[j]=c} A[256+i][j] (constant).
// 1024 thr = 16 waves = 4 row-chunks x 4 j-slices; lane = row (wave-uniform Xs reads
// -> LDS broadcast); A_uu slice in 64 VGPRs, fully unrolled (rule #20).
__global__ __launch_bounds__(1024)
void gtg1(const float* __restrict__ A, const int* __restrict__ labels,
          float* __restrict__ out) {
  const int tid = threadIdx.x;
  const int w = tid >> 6, l = tid & 63;
  const int rc = w & 3, g = w >> 2;
  const int i = rc * 64 + l;              // unlabeled row 0..255 (global 256+i)
  __shared__ float Xs[256][12];
  __shared__ float Ls[256][12];
  __shared__ float axred[4][256][12];
  __shared__ float dredw[4];
  __shared__ int labs[256];

  if (tid < 256) labs[tid] = labels[tid];
  for (int e = tid; e < 256 * 12; e += 1024)
    (&Xs[0][0])[e] = ((e % 12) < 10) ? 0.1f : 0.f;
  __syncthreads();

  const float* Ar = A + (size_t)(256 + i) * 512;
  float areg[64];
#pragma unroll
  for (int q = 0; q < 16; ++q) {
    float4 v = *(const float4*)(Ar + 256 + g * 64 + q * 4);
    areg[q * 4 + 0] = v.x; areg[q * 4 + 1] = v.y;
    areg[q * 4 + 2] = v.z; areg[q * 4 + 3] = v.w;
  }
  {  // labeled-column contribution partial
    float lp[10];
#pragma unroll
    for (int c = 0; c < 10; ++c) lp[c] = 0.f;
    for (int q = 0; q < 16; ++q) {
      float4 v = *(const float4*)(Ar + g * 64 + q * 4);
      float av[4] = {v.x, v.y, v.z, v.w};
#pragma unroll
      for (int k = 0; k < 4; ++k) {
        int lab = labs[g * 64 + q * 4 + k];
#pragma unroll
        for (int c = 0; c < 10; ++c) lp[c] += (lab == c) ? av[k] : 0.f;
      }
    }
    *(float4*)&axred[g][i][0] = make_float4(lp[0], lp[1], lp[2], lp[3]);
    *(float4*)&axred[g][i][4] = make_float4(lp[4], lp[5], lp[6], lp[7]);
    *(float2*)&axred[g][i][8] = make_float2(lp[8], lp[9]);
  }
  __syncthreads();
  if (g == 0) {
    float s[10];
#pragma unroll
    for (int c = 0; c < 10; ++c) s[c] = 0.f;
#pragma unroll
    for (int q = 0; q < 4; ++q) {
      float4 a0 = *(const float4*)&axred[q][i][0];
      float4 a1 = *(const float4*)&axred[q][i][4];
      float2 a2 = *(const float2*)&axred[q][i][8];
      s[0] += a0.x; s[1] += a0.y; s[2] += a0.z; s[3] += a0.w;
      s[4] += a1.x; s[5] += a1.y; s[6] += a1.z; s[7] += a1.w;
      s[8] += a2.x; s[9] += a2.y;
    }
    *(float4*)&Ls[i][0] = make_float4(s[0], s[1], s[2], s[3]);
    *(float4*)&Ls[i][4] = make_float4(s[4], s[5], s[6], s[7]);
    *(float2*)&Ls[i][8] = make_float2(s[8], s[9]);
  }
  __syncthreads();

  float entsum = 0.f;
  float nrm2 = 1e30f;
  for (int it = 0; it < kMaxIter; ++it) {
    if (it > 0 && sqrtf(nrm2) <= 0.001f) break;
    float ax[10];
#pragma unroll
    for (int c = 0; c < 10; ++c) ax[c] = 0.f;
#pragma unroll
    for (int jj = 0; jj < 64; ++jj) {        // wave-uniform j -> LDS broadcast
      const int j = g * 64 + jj;
      float4 x0 = *(const float4*)&Xs[j][0];
      float4 x1 = *(const float4*)&Xs[j][4];
      float2 x2 = *(const float2*)&Xs[j][8];
      float a = areg[jj];
      ax[0] = fmaf(a, x0.x, ax[0]); ax[1] = fmaf(a, x0.y, ax[1]);
      ax[2] = fmaf(a, x0.z, ax[2]); ax[3] = fmaf(a, x0.w, ax[3]);
      ax[4] = fmaf(a, x1.x, ax[4]); ax[5] = fmaf(a, x1.y, ax[5]);
      ax[6] = fmaf(a, x1.z, ax[6]); ax[7] = fmaf(a, x1.w, ax[7]);
      ax[8] = fmaf(a, x2.x, ax[8]); ax[9] = fmaf(a, x2.y, ax[9]);
    }
    *(float4*)&axred[g][i][0] = make_float4(ax[0], ax[1], ax[2], ax[3]);
    *(float4*)&axred[g][i][4] = make_float4(ax[4], ax[5], ax[6], ax[7]);
    *(float2*)&axred[g][i][8] = make_float2(ax[8], ax[9]);
    __syncthreads();
    if (g == 0) {
      float s[10];
#pragma unroll
      for (int c = 0; c < 10; ++c) s[c] = Ls[i][c];
#pragma unroll
      for (int q = 0; q < 4; ++q) {
        float4 a0 = *(const float4*)&axred[q][i][0];
        float4 a1 = *(const float4*)&axred[q][i][4];
        float2 a2 = *(const float2*)&axred[q][i][8];
        s[0] += a0.x; s[1] += a0.y; s[2] += a0.z; s[3] += a0.w;
        s[4] += a1.x; s[5] += a1.y; s[6] += a1.z; s[7] += a1.w;
        s[8] += a2.x; s[9] += a2.y;
      }
      float xn[10], ssum = 0.f;
#pragma unroll
      for (int c = 0; c < 10; ++c) { xn[c] = Xs[i][c] * s[c]; ssum += xn[c]; }
      float ent = 0.f, dp = 0.f;
#pragma unroll
      for (int c = 0; c < 10; ++c) {
        float xv = xn[c] / ssum;
        if (xv > 0.f) ent -= xv * logf(xv);
        float d = xv - Xs[i][c];
        dp += d * d;
        Xs[i][c] = xv;
      }
      entsum += ent;
#pragma unroll
      for (int m = 1; m < 64; m <<= 1) dp += __shfl_xor(dp, m);
      if (l == 0) dredw[rc] = dp;
    }
    __syncthreads();
    nrm2 = dredw[0] + dredw[1] + dredw[2] + dredw[3];
  }

  // ---- outputs ----
  if (g == 0) out[512 + 256 + i] = entsum * (1.0f / 30.0f);   // unlabeled y_true
  for (int e = tid; e < 256; e += 1024) {
    out[512 + e] = 0.f;            // labeled y_true (entropy of one-hot = 0)
    out[6144 + e] = 1.f;           // mask labeled
    out[6144 + 256 + e] = 0.f;     // mask unlabeled
  }
  for (int e = tid; e < 2560; e += 1024) {
    int r = e / 10, c = e % 10;
    out[1024 + e] = (labs[r] == c) ? 1.f : 0.f;   // labeled X (exact one-hot)
    out[1024 + 2560 + e] = Xs[r][c];              // unlabeled X
  }
}

extern "C" void kernel_launch(void* const* d_in, const int* in_sizes, int n_in,
                              void* d_out, int out_size, void* d_ws, size_t ws_size,
                              hipStream_t stream) {
  (void)in_sizes; (void)n_in; (void)out_size;

  const float* feat[4]; const float* cw[4]; const float* cbp[4];
  const float* bg[4]; const float* bbp[4]; const float* lw[4]; const float* lbp[4];
  for (int b = 0; b < 4; ++b) {
    int base = b * 7;
    feat[b] = (const float*)d_in[base + 0];
    cw[b]  = (const float*)d_in[base + 1];
    cbp[b] = (const float*)d_in[base + 2];
    bg[b]  = (const float*)d_in[base + 3];
    bbp[b] = (const float*)d_in[base + 4];
    lw[b]  = (const float*)d_in[base + 5];
    lbp[b] = (const float*)d_in[base + 6];
  }
  const float* finw = (const float*)d_in[28];
  const float* finb = (const float*)d_in[29];
  const float* emb  = (const float*)d_in[30];
  const int* labels = (const int*)d_in[31];
  float* out = (float*)d_out;

  // ---- workspace layout (float offsets) ----
  float* wsf = (float*)d_ws;
  unsigned short* xpad = (unsigned short*)wsf;                    // 16.78 MB
  unsigned short* yP   = (unsigned short*)(wsf + 4194304);        // 33.55 MB
  unsigned short* wpk  = (unsigned short*)(wsf + 12582912);       // 6.27 MB
  size_t off = 14149632;
  float* psum = wsf + off; off += 524288;
  float* psq  = wsf + off; off += 524288;
  float* pp   = wsf + off; off += 524288;
  float* scale = wsf + off; off += 512;
  float* shift = wsf + off; off += 512;
  float* pooled = wsf + off; off += 491520;
  float* oc = wsf + off; off += 262144;
  float* sq = wsf + off; off += 512;
  float* A0 = wsf + off; off += 262144;
  float* Am = wsf + off; off += 262144;
  float* sig = wsf + off; off += 512;
  int* idx7 = (int*)(wsf + off); off += 512;
  float* meanPart = wsf + off; off += 256;
  float* meanA = wsf + off; off += 4;
  size_t yb0_off = off;
  unsigned short* yB0 = (unsigned short*)(wsf + yb0_off);         // 67.1 MB (optional)
  const bool bigB0 = ws_size >= (yb0_off + 16777216) * sizeof(float);

  unsigned short* wpkB[4] = {wpk, wpk + 36864, wpk + 184320, wpk + 774144};

  wpack_all<<<(3133440 + 255) / 256, 256, 0, stream>>>(cw[0], cw[1], cw[2], cw[3], wpk);

  // ===== branch 1: C=128, S=16 (xpad chunked x2) =====
  for (int c = 0; c < 2; ++c) {
    xpack_kernel<128, 16><<<256 * 16, 256, 0, stream>>>(feat[1] + (size_t)c * 8388608, xpad);
    conv_mfma<128, 16, 1, 8, 4, 2, 0><<<dim3(512, 2), 256, 0, stream>>>(
        xpad, wpkB[1], cbp[1], yP + (size_t)c * 8388608, psum, psq, 4096, c * 2048,
        nullptr, nullptr, nullptr, 0);
  }
  stats2_kernel<<<128, 256, 0, stream>>>(psum, psq, bg[1], bbp[1], scale, shift, 4096, 1.f / 131072.f);
  pool_lin<128, 16><<<512, 256, 0, stream>>>(yP, scale, shift, lw[1], lbp[1], oc, 128);

  // ===== branch 2: C=256, S=8 =====
  xpack_kernel<256, 8><<<512 * 8, 256, 0, stream>>>(feat[2], xpad);
  conv_mfma<256, 8, 2, 8, 4, 2, 0><<<dim3(256, 4), 256, 0, stream>>>(
      xpad, wpkB[2], cbp[2], yP, psum, psq, 1024, 0, nullptr, nullptr, nullptr, 0);
  stats2_kernel<<<256, 256, 0, stream>>>(psum, psq, bg[2], bbp[2], scale, shift, 1024, 1.f / 32768.f);
  pool_lin<256, 8><<<512, 256, 0, stream>>>(yP, scale, shift, lw[2], lbp[2], oc, 256);

  // ===== branch 3: C=512, S=4 =====
  xpack_kernel<512, 4><<<512 * 4, 256, 0, stream>>>(feat[3], xpad);
  conv_mfma<512, 4, 8, 4, 4, 2, 0><<<dim3(64, 8), 256, 0, stream>>>(
      xpad, wpkB[3], cbp[3], yP, psum, psq, 256, 0, nullptr, nullptr, nullptr, 0);
  stats2_kernel<<<512, 256, 0, stream>>>(psum, psq, bg[3], bbp[3], scale, shift, 256, 1.f / 8192.f);
  pool_lin<512, 4><<<512, 256, 0, stream>>>(yP, scale, shift, lw[3], lbp[3], oc, 384);

  // ===== branch 0: C=64, S=32 =====
  if (bigB0) {
    for (int c = 0; c < 4; ++c) {
      xpack_kernel<64, 32><<<128 * 32, 256, 0, stream>>>(feat[0] + (size_t)c * 8388608, xpad);
      conv_mfma<64, 32, 1, 8, 4, 4, 0><<<dim3(512, 1), 256, 0, stream>>>(
          xpad, wpkB[0], cbp[0], yB0 + (size_t)c * 8388608, psum, psq, 8192, c * 2048,
          nullptr, nullptr, nullptr, 0);
    }
    stats2_kernel<<<64, 256, 0, stream>>>(psum, psq, bg[0], bbp[0], scale, shift, 8192, 1.f / 524288.f);
    pool_lin<64, 32><<<512, 256, 0, stream>>>(yB0, scale, shift, lw[0], lbp[0], oc, 0);
  } else {
    for (int c = 0; c < 4; ++c) {
      xpack_kernel<64, 32><<<128 * 32, 256, 0, stream>>>(feat[0] + (size_t)c * 8388608, xpad);
      conv_mfma<64, 32, 1, 8, 4, 4, 1><<<dim3(512, 1), 256, 0, stream>>>(
          xpad, wpkB[0], cbp[0], nullptr, psum, psq, 8192, c * 2048, nullptr, nullptr, nullptr, 0);
    }
    stats2_kernel<<<64, 256, 0, stream>>>(psum, psq, bg[0], bbp[0], scale, shift, 8192, 1.f / 524288.f);
    for (int c = 0; c < 4; ++c) {
      xpack_kernel<64, 32><<<128 * 32, 256, 0, stream>>>(feat[0] + (size_t)c * 8388608, xpad);
      conv_mfma<64, 32, 1, 8, 4, 4, 2><<<dim3(512, 1), 256, 0, stream>>>(
          xpad, wpkB[0], cbp[0], nullptr, nullptr, nullptr, 0, 0, scale, shift, pp, c * 131072);
    }
    poolfin_kernel<<<128, 256, 0, stream>>>(pp, pooled);
    lin_kernel<<<256, 256, 0, stream>>>(pooled, lw[0], lbp[0], oc, 64, 0);
  }

  // ===== head + GTG =====
  ypred_kernel<<<128, 256, 0, stream>>>(oc, finw, finb, out);
  sqnorm_kernel<<<128, 256, 0, stream>>>(emb, sq);
  a0_kernel<<<1024, 256, 0, stream>>>(emb, sq, A0);
  seventh_kernel<<<2, 256, 0, stream>>>(A0, idx7);
  sig_kernel<<<128, 256, 0, stream>>>(emb, idx7, sig);
  aexp_kernel<<<256, 256, 0, stream>>>(A0, sig, Am, meanPart);
  meanred_kernel<<<1, 64, 0, stream>>>(meanPart, meanA);
  thresh_kernel<<<256, 256, 0, stream>>>(Am, meanA);

  gtg1<<<1, 1024, 0, stream>>>(Am, labels, out);
}

// Round 10
// 997.505 us; speedup vs baseline: 1.0104x; 1.0104x over previous
//
#include <hip/hip_runtime.h>
#include <hip/hip_bf16.h>
#include <math.h>

static constexpr int kNC = 10;
static constexpr int kNLab = 256;
static constexpr int kMaxIter = 30;

using short8 = __attribute__((ext_vector_type(8))) short;
using f32x4  = __attribute__((ext_vector_type(4))) float;

__device__ __forceinline__ unsigned short f2bf(float f) {
  unsigned int u = __float_as_uint(f);
  u += 0x7FFFu + ((u >> 16) & 1u);   // RNE
  return (unsigned short)(u >> 16);
}
__device__ __forceinline__ float bf2f(unsigned short u) {
  return __uint_as_float(((unsigned int)u) << 16);
}

// ---------------- NCHW fp32 -> NHWC bf16 transpose (per (n,h) row) ----------------
template <int C, int S>
__global__ __launch_bounds__(256) void xpack_kernel(const float* __restrict__ x,
                                                    unsigned short* __restrict__ xp) {
  __shared__ float t[C][S + 1];
  const int n = blockIdx.x / S, h = blockIdx.x % S;
  const float* src = x + (size_t)n * C * S * S;
  for (int e = threadIdx.x; e < C * S; e += 256) {
    int c = e / S, w = e % S;
    t[c][w] = src[((size_t)c * S + h) * S + w];
  }
  __syncthreads();
  unsigned short* dst = xp + ((size_t)(n * S + h) * S) * C;
  for (int e = threadIdx.x; e < C * S; e += 256) {
    int w = e / C, c = e % C;
    dst[(size_t)w * C + c] = f2bf(t[c][w]);
  }
}

// ---------------- all-branch weight pack into MFMA A-fragment order bf16 ----------
// per-branch layout: [tap][cik][co16][lane][8]; co=co16*16+(l&15), ci=cik*32+(l>>4)*8+e
__global__ void wpack_all(const float* __restrict__ w0, const float* __restrict__ w1,
                          const float* __restrict__ w2, const float* __restrict__ w3,
                          unsigned short* __restrict__ wpk) {
  int idx = blockIdx.x * 256 + threadIdx.x;
  if (idx >= 3133440) return;
  const float* w; int C, off;
  if (idx < 36864)        { w = w0; C = 64;  off = 0; }
  else if (idx < 184320)  { w = w1; C = 128; off = 36864; }
  else if (idx < 774144)  { w = w2; C = 256; off = 184320; }
  else                    { w = w3; C = 512; off = 774144; }
  int e = idx - off;
  int CO16T = C / 16, CIK = C / 32;
  int e8 = e & 7, l = (e >> 3) & 63;
  int rest = e >> 9;
  int co16 = rest % CO16T;
  int rest2 = rest / CO16T;
  int cik = rest2 % CIK, tap = rest2 / CIK;
  int co = co16 * 16 + (l & 15);
  int ci = cik * 32 + (l >> 4) * 8 + e8;
  wpk[idx] = f2bf(w[((size_t)co * C + ci) * 9 + tap]);
}

// ---------------- MFMA implicit-GEMM 3x3 SAME conv ----------------
// block: WV waves; px-tile PXB = NI*NR*S; per-wave BF 16-px fragments; 64 co per block.
// MODE 0: store y(NHWC bf16)+stats partials; 1: stats only; 2: fused BN+relu+pool partials
template <int C, int S, int NI, int NR, int WV, int BF, int MODE>
__global__ __launch_bounds__(WV * 64)
void conv_mfma(const unsigned short* __restrict__ xp, const unsigned short* __restrict__ wpk,
               const float* __restrict__ bias, unsigned short* __restrict__ y,
               float* __restrict__ psum, float* __restrict__ psq, int npart, int partBase,
               const float* __restrict__ scale, const float* __restrict__ shift,
               float* __restrict__ pp, int pxGlobalBase) {
  constexpr int SS = S * S;
  constexpr int PXB = NI * NR * S;
  constexpr int TPB = WV * 64;
  constexpr int HR = NR + 2, HC = S + 2;
  constexpr int CIK = C / 32, CO16T = C / 16;
  constexpr int UNITS = NI * HR * HC * 4;
  constexpr int NU = (UNITS + TPB - 1) / TPB;
  static_assert(WV * BF * 16 == PXB, "wave px mismatch");
  static_assert(MODE != 2 || BF == 4, "MODE2 assumes 64px/wave");
  __shared__ __align__(16) char xs[NI * HR * HC * 80];

  const int tid = threadIdx.x;
  const int wv = tid >> 6, l = tid & 63, l15 = l & 15, l4 = l >> 4;
  const int coblk = blockIdx.y;
  const int co_base = coblk * 64;
  const int pxb = blockIdx.x * PXB;
  const int n_t = pxb / SS;
  const int r0 = (pxb % SS) / S;

  int pxoff[BF];
#pragma unroll
  for (int bf = 0; bf < BF; ++bf) {
    int pxloc = wv * (BF * 16) + bf * 16 + l15;
    int ii = pxloc / (NR * S);
    int rr = (pxloc % (NR * S)) / S;
    int cc = pxloc % S;
    pxoff[bf] = ((ii * HR + rr) * HC + cc) * 80 + l4 * 16;
  }

  f32x4 acc[4][BF];
#pragma unroll
  for (int a = 0; a < 4; ++a)
#pragma unroll
    for (int b = 0; b < BF; ++b) acc[a][b] = (f32x4){0.f, 0.f, 0.f, 0.f};

  uint4 vreg[NU];
  auto loadU = [&](int cik) {
#pragma unroll
    for (int k = 0; k < NU; ++k) {
      int u = tid + k * TPB;
      uint4 v = {0u, 0u, 0u, 0u};
      if (u < UNITS) {
        int k16 = u & 3;
        int t = u >> 2;
        int hc = t % HC;
        int t2 = t / HC;
        int hr = t2 % HR;
        int ii = t2 / HR;
        int row = r0 + hr - 1, col = hc - 1;
        if (row >= 0 && row < S && col >= 0 && col < S)
          v = *(const uint4*)(xp + ((size_t)((n_t + ii) * S + row) * S + col) * C + cik * 32 + k16 * 8);
      }
      vreg[k] = v;
    }
  };

  loadU(0);
  for (int cik = 0; cik < CIK; ++cik) {
    __syncthreads();     // previous readers done
#pragma unroll
    for (int k = 0; k < NU; ++k) {
      int u = tid + k * TPB;
      if (u < UNITS) *(uint4*)(xs + (u >> 2) * 80 + (u & 3) * 16) = vreg[k];
    }
    __syncthreads();
    if (cik + 1 < CIK) loadU(cik + 1);   // in flight during MFMA phase
#pragma unroll
    for (int tap = 0; tap < 9; ++tap) {
      const int tapoff = ((tap / 3) * HC + (tap % 3)) * 80;
      short8 wf[4], xf[BF];
#pragma unroll
      for (int af = 0; af < 4; ++af)
        wf[af] = *(const short8*)(wpk + ((size_t)((tap * CIK + cik) * CO16T + coblk * 4 + af) * 64 + l) * 8);
#pragma unroll
      for (int bf = 0; bf < BF; ++bf)
        xf[bf] = *(const short8*)(xs + pxoff[bf] + tapoff);
#pragma unroll
      for (int af = 0; af < 4; ++af)
#pragma unroll
        for (int bf = 0; bf < BF; ++bf)
          acc[af][bf] = __builtin_amdgcn_mfma_f32_16x16x32_bf16(wf[af], xf[bf], acc[af][bf], 0, 0, 0);
    }
  }

  // ---------------- epilogue ----------------
#pragma unroll
  for (int af = 0; af < 4; ++af) {
    const int co0 = co_base + af * 16 + l4 * 4;
    float4 bv = *(const float4*)(bias + co0);
    float s[4] = {0.f, 0.f, 0.f, 0.f}, q[4] = {0.f, 0.f, 0.f, 0.f};
    float4 sc4, sh4;
    if (MODE == 2) {
      sc4 = *(const float4*)(scale + co0);
      sh4 = *(const float4*)(shift + co0);
    }
#pragma unroll
    for (int bf = 0; bf < BF; ++bf) {
      float o[4];
#pragma unroll
      for (int r = 0; r < 4; ++r) o[r] = acc[af][bf][r] + ((const float*)&bv)[r];
      if (MODE == 0) {
        ushort4 pk;
        pk.x = f2bf(o[0]); pk.y = f2bf(o[1]); pk.z = f2bf(o[2]); pk.w = f2bf(o[3]);
        size_t px = (size_t)(pxb + wv * (BF * 16) + bf * 16 + l15);
        *(ushort4*)(y + px * C + co0) = pk;
      }
      if (MODE == 2) {
#pragma unroll
        for (int r = 0; r < 4; ++r)
          s[r] += fmaxf(fmaf(((const float*)&sc4)[r], o[r], ((const float*)&sh4)[r]), 0.f);
      } else {
#pragma unroll
        for (int r = 0; r < 4; ++r) { s[r] += o[r]; q[r] += o[r] * o[r]; }
      }
    }
#pragma unroll
    for (int m = 1; m < 16; m <<= 1) {
#pragma unroll
      for (int r = 0; r < 4; ++r) {
        s[r] += __shfl_xor(s[r], m);
        if (MODE != 2) q[r] += __shfl_xor(q[r], m);
      }
    }
    if (l15 == 0) {
      if (MODE == 2) {
        int n = (pxGlobalBase + pxb) / SS;
        int qw = ((pxGlobalBase + pxb) % SS) / 64 + wv;
#pragma unroll
        for (int r = 0; r < 4; ++r)
          pp[((size_t)(n * C + co0 + r)) * 16 + qw] = s[r];
      } else {
        int part = partBase + blockIdx.x * WV + wv;
#pragma unroll
        for (int r = 0; r < 4; ++r) {
          psum[(size_t)(co0 + r) * npart + part] = s[r];
          psq[(size_t)(co0 + r) * npart + part] = q[r];
        }
      }
    }
  }
}

// ---------------- BN stats finalize (deterministic tree) ----------------
__global__ __launch_bounds__(256)
void stats2_kernel(const float* __restrict__ psum, const float* __restrict__ psq,
                   const float* __restrict__ g, const float* __restrict__ bb,
                   float* __restrict__ scale, float* __restrict__ shift,
                   int npart, float invN) {
  int c = blockIdx.x;
  __shared__ float rs[256], rq[256];
  float s = 0.f, q = 0.f;
  for (int p = threadIdx.x; p < npart; p += 256) {
    s += psum[(size_t)c * npart + p];
    q += psq[(size_t)c * npart + p];
  }
  rs[threadIdx.x] = s; rq[threadIdx.x] = q;
  __syncthreads();
  for (int st = 128; st; st >>= 1) {
    if (threadIdx.x < st) { rs[threadIdx.x] += rs[threadIdx.x + st]; rq[threadIdx.x] += rq[threadIdx.x + st]; }
    __syncthreads();
  }
  if (threadIdx.x == 0) {
    float m = rs[0] * invN;
    float v = rq[0] * invN - m * m;
    float sc = g[c] / sqrtf(v + 1e-5f);
    scale[c] = sc;
    shift[c] = bb[c] - m * sc;
  }
}

// ---------------- fused relu(bn(y NHWC)) spatial mean + linear -> oc ----------------
template <int C, int S>
__global__ __launch_bounds__(256)
void pool_lin(const unsigned short* __restrict__ y, const float* __restrict__ scale,
              const float* __restrict__ shift, const float* __restrict__ lw,
              const float* __restrict__ lb, float* __restrict__ oc, int brOff) {
  constexpr int SS = S * S;
  int n = blockIdx.x;
  const unsigned short* yr = y + (size_t)n * SS * C;
  __shared__ float pl[C];
  if (C >= 256) {
    for (int co = threadIdx.x; co < C; co += 256) {
      float sc = scale[co], sh = shift[co], s = 0.f;
      for (int p = 0; p < SS; ++p) s += fmaxf(fmaf(sc, bf2f(yr[(size_t)p * C + co]), sh), 0.f);
      pl[co] = s * (1.f / SS);
    }
  } else {
    constexpr int G = 256 / C;
    int co = threadIdx.x % C;
    int sl = threadIdx.x / C;
    float sc = scale[co], sh = shift[co], s = 0.f;
    for (int p = sl; p < SS; p += G) s += fmaxf(fmaf(sc, bf2f(yr[(size_t)p * C + co]), sh), 0.f);
    __shared__ float red[256];
    red[threadIdx.x] = s;
    __syncthreads();
    if (threadIdx.x < C) {
      float t = 0.f;
      for (int gg = 0; gg < G; ++gg) t += red[gg * C + co];
      pl[co] = t * (1.f / SS);
    }
  }
  __syncthreads();
  if (threadIdx.x < 128) {
    int j = threadIdx.x;
    const float* wr = lw + (size_t)j * C;
    float s = 0.f;
    for (int t = 0; t < C; ++t) s = fmaf(pl[t], wr[t], s);
    s += lb[j];
    oc[n * 512 + brOff + j] = fmaxf(s, 0.f);
  }
}

// ---------------- branch-0 fallback fused-pool finalize ----------------
__global__ void poolfin_kernel(const float* __restrict__ pp, float* __restrict__ pooled) {
  int i = blockIdx.x * 256 + threadIdx.x;
  if (i >= 512 * 64) return;
  float s = 0.f;
  for (int qn = 0; qn < 16; ++qn) s += pp[(size_t)i * 16 + qn];
  pooled[i] = s * (1.f / 1024.f);
}

// ---------------- relu(pooled @ lw.T + lb) -> oc[n][512] at brOff (fallback) -------
__global__ void lin_kernel(const float* __restrict__ pooled, const float* __restrict__ lw,
                           const float* __restrict__ lb, float* __restrict__ oc,
                           int C, int brOff) {
  int idx = blockIdx.x * 256 + threadIdx.x;
  if (idx >= 512 * 128) return;
  int j = idx & 127, n = idx >> 7;
  const float4* pr = (const float4*)(pooled + (size_t)n * C);
  const float4* wr = (const float4*)(lw + (size_t)j * C);
  float s = 0.f;
  for (int t = 0; t < C / 4; ++t) {
    float4 a = pr[t], b = wr[t];
    s += a.x * b.x + a.y * b.y + a.z * b.z + a.w * b.w;
  }
  s += lb[j];
  oc[n * 512 + brOff + j] = fmaxf(s, 0.f);
}

__global__ void ypred_kernel(const float* __restrict__ oc, const float* __restrict__ fw,
                             const float* __restrict__ fb, float* __restrict__ out) {
  int wv = threadIdx.x >> 6, l = threadIdx.x & 63;
  int n = blockIdx.x * 4 + wv;
  float s = 0.f;
  for (int k = l; k < 512; k += 64) s += oc[n * 512 + k] * fw[k];
#pragma unroll
  for (int m = 32; m; m >>= 1) s += __shfl_down(s, m);
  if (l == 0) out[n] = s + fb[0];
}

// ---------------- GTG graph build ----------------
__global__ void sqnorm_kernel(const float* __restrict__ E, float* __restrict__ sq) {
  int wv = threadIdx.x >> 6, l = threadIdx.x & 63;
  int n = blockIdx.x * 4 + wv;
  const float* row = E + (size_t)n * 512;
  float s = 0.f;
  for (int k = l; k < 512; k += 64) { float v = row[k]; s += v * v; }
#pragma unroll
  for (int m = 32; m; m >>= 1) s += __shfl_down(s, m);
  if (l == 0) sq[n] = s;
}

__global__ __launch_bounds__(256) void a0_kernel(const float* __restrict__ E,
                                                 const float* __restrict__ sq,
                                                 float* __restrict__ A0) {
  int bi = blockIdx.x / 32, bj = blockIdx.x % 32;
  int ti = threadIdx.x % 16, tj = threadIdx.x / 16;
  __shared__ float Ei[16][68], Ej[16][68];
  float acc = 0.f;
  for (int k0 = 0; k0 < 512; k0 += 64) {
    for (int e = threadIdx.x; e < 1024; e += 256) {
      int rr = e >> 6, cc = e & 63;
      Ei[rr][cc] = E[(size_t)(bi * 16 + rr) * 512 + k0 + cc];
      Ej[rr][cc] = E[(size_t)(bj * 16 + rr) * 512 + k0 + cc];
    }
    __syncthreads();
#pragma unroll 16
    for (int kk = 0; kk < 64; ++kk) acc = fmaf(Ei[tj][kk], Ej[ti][kk], acc);
    __syncthreads();
  }
  int i = bi * 16 + tj, j = bj * 16 + ti;
  float d2 = fmaxf(sq[i] + sq[j] - 2.f * acc, 0.f);
  A0[(size_t)i * 512 + j] = fminf(fmaxf(sqrtf(d2), 0.1f), 1.0f);
}

__global__ void seventh_kernel(const float* __restrict__ A0, int* __restrict__ idx7) {
  int i = blockIdx.x * 256 + threadIdx.x;
  if (i >= 512) return;
  float v[7]; int ix[7];
#pragma unroll
  for (int t = 0; t < 7; ++t) { v[t] = 3.4e38f; ix[t] = 0; }
  const float* row = A0 + (size_t)i * 512;
  for (int j = 0; j < 512; ++j) {
    float a = row[j];
    if (a < v[6]) {
      int pos = 6;
      while (pos > 0 && a < v[pos - 1]) { v[pos] = v[pos - 1]; ix[pos] = ix[pos - 1]; --pos; }
      v[pos] = a; ix[pos] = j;
    }
  }
  idx7[i] = ix[6];
}

__global__ void sig_kernel(const float* __restrict__ E, const int* __restrict__ idx7,
                           float* __restrict__ sig) {
  int wv = threadIdx.x >> 6, l = threadIdx.x & 63;
  int n = blockIdx.x * 4 + wv;
  const float* r1 = E + (size_t)n * 512;
  const float* r2 = E + (size_t)idx7[n] * 512;
  float s = 0.f;
  for (int k = l; k < 512; k += 64) { float d = r1[k] - r2[k]; s += d * d; }
#pragma unroll
  for (int m = 32; m; m >>= 1) s += __shfl_down(s, m);
  if (l == 0) sig[n] = fminf(fmaxf(sqrtf(s), 0.1f), 1.0f);
}

__global__ void aexp_kernel(const float* __restrict__ A0, const float* __restrict__ sig,
                            float* __restrict__ A, float* __restrict__ part) {
  int t = blockIdx.x * 256 + threadIdx.x;
  int base = t * 4;
  int i = base >> 9, j0 = base & 511;
  float si = sig[i];
  float4 a = *(const float4*)(A0 + base);
  float4 o;
  o.x = fminf(fmaxf(expf(-a.x * a.x / (si * sig[j0 + 0])), 0.f), 1.f);
  o.y = fminf(fmaxf(expf(-a.y * a.y / (si * sig[j0 + 1])), 0.f), 1.f);
  o.z = fminf(fmaxf(expf(-a.z * a.z / (si * sig[j0 + 2])), 0.f), 1.f);
  o.w = fminf(fmaxf(expf(-a.w * a.w / (si * sig[j0 + 3])), 0.f), 1.f);
  *(float4*)(A + base) = o;
  float lsum = o.x + o.y + o.z + o.w;
#pragma unroll
  for (int m = 32; m; m >>= 1) lsum += __shfl_down(lsum, m);
  __shared__ float sred[4];
  if ((threadIdx.x & 63) == 0) sred[threadIdx.x >> 6] = lsum;
  __syncthreads();
  if (threadIdx.x == 0) part[blockIdx.x] = sred[0] + sred[1] + sred[2] + sred[3];
}

__global__ void meanred_kernel(const float* __restrict__ part, float* __restrict__ meanA) {
  if (threadIdx.x == 0 && blockIdx.x == 0) {
    float s = 0.f;
    for (int p = 0; p < 256; ++p) s += part[p];
    meanA[0] = s * (1.0f / 262144.0f);
  }
}

__global__ void thresh_kernel(float* __restrict__ A, const float* __restrict__ meanA) {
  int t = blockIdx.x * 256 + threadIdx.x;
  int base = t * 4;
  int i = base >> 9, j0 = base & 511;
  float m = meanA[0];
  float4 v = *(const float4*)(A + base);
  v.x = v.x > m ? 1.f : v.x;
  v.y = v.y > m ? 1.f : v.y;
  v.z = v.z > m ? 1.f : v.z;
  v.w = v.w > m ? 1.f : v.w;
  if (i < kNLab && j0 < kNLab) {
    v.x = 1.f - v.x; v.y = 1.f - v.y; v.z = 1.f - v.z; v.w = 1.f - v.w;
  }
  *(float4*)(A + base) = v;
}

// ---------------- replicator: SINGLE block, in-wave reduction, no spill -----------
// wave w (0..15) owns rows i = w*16 + (l&15); lane's j-slice g = l>>4 covers 64 cols.
// A_uu slice in areg[64] (VGPRs; __launch_bounds__(1024,4) caps VGPR at 128 -> fits).
// Labeled contribution lp[10] per-lane constant, folded into the shfl_xor reduce.
// Cross-slice reduce via __shfl_xor(16/32); 1 barrier/iter; Xs + dredw double-buffered.
__global__ __launch_bounds__(1024, 4)
void gtg2(const float* __restrict__ A, const int* __restrict__ labels,
          float* __restrict__ out) {
  const int tid = threadIdx.x;
  const int w = tid >> 6, l = tid & 63;
  const int r = l & 15, g = l >> 4;
  const int i = w * 16 + r;                 // unlabeled row 0..255 (global 256+i)
  __shared__ float Xs[2][256][12];
  __shared__ float dredw[2][16];
  __shared__ int labs[256];

  if (tid < 256) labs[tid] = labels[tid];
  for (int e = tid; e < 256 * 12; e += 1024)
    (&Xs[0][0][0])[e] = ((e % 12) < 10) ? 0.1f : 0.f;
  __syncthreads();

  // A slice: row 256+i, cols g*64.. (labeled) and 256+g*64.. (unlabeled)
  const float* Ar = A + (size_t)(256 + i) * 512 + g * 64;
  float areg[64];
#pragma unroll
  for (int q = 0; q < 16; ++q) {
    float4 v = *(const float4*)(Ar + 256 + q * 4);
    areg[q * 4 + 0] = v.x; areg[q * 4 + 1] = v.y;
    areg[q * 4 + 2] = v.z; areg[q * 4 + 3] = v.w;
  }
  float lp[10];
#pragma unroll
  for (int c = 0; c < 10; ++c) lp[c] = 0.f;
#pragma unroll
  for (int q = 0; q < 16; ++q) {
    float4 v = *(const float4*)(Ar + q * 4);
    float av[4] = {v.x, v.y, v.z, v.w};
#pragma unroll
    for (int k = 0; k < 4; ++k) {
      int lab = labs[g * 64 + q * 4 + k];
#pragma unroll
      for (int c = 0; c < 10; ++c) lp[c] += (lab == c) ? av[k] : 0.f;
    }
  }

  float entsum = 0.f;
  float nrm2 = 1e30f;
  int cur = 0;
  for (int it = 0; it < kMaxIter; ++it) {
    if (it > 0 && sqrtf(nrm2) <= 0.001f) break;
    float ax[10];
#pragma unroll
    for (int c = 0; c < 10; ++c) ax[c] = lp[c];
#pragma unroll
    for (int jj = 0; jj < 64; ++jj) {
      const float* xr = &Xs[cur][g * 64 + jj][0];
      float4 x0 = *(const float4*)(xr);
      float4 x1 = *(const float4*)(xr + 4);
      float2 x2 = *(const float2*)(xr + 8);
      float a = areg[jj];
      ax[0] = fmaf(a, x0.x, ax[0]); ax[1] = fmaf(a, x0.y, ax[1]);
      ax[2] = fmaf(a, x0.z, ax[2]); ax[3] = fmaf(a, x0.w, ax[3]);
      ax[4] = fmaf(a, x1.x, ax[4]); ax[5] = fmaf(a, x1.y, ax[5]);
      ax[6] = fmaf(a, x1.z, ax[6]); ax[7] = fmaf(a, x1.w, ax[7]);
      ax[8] = fmaf(a, x2.x, ax[8]); ax[9] = fmaf(a, x2.y, ax[9]);
    }
    // combine the 4 j-slices (and the lp constants) across the wave
#pragma unroll
    for (int c = 0; c < 10; ++c) {
      ax[c] += __shfl_xor(ax[c], 16);
      ax[c] += __shfl_xor(ax[c], 32);
    }
    float dp = 0.f;
    if (g == 0) {                      // lanes 0..15 renorm their row
      float xn[10], ssum = 0.f;
#pragma unroll
      for (int c = 0; c < 10; ++c) { xn[c] = Xs[cur][i][c] * ax[c]; ssum += xn[c]; }
      float ent = 0.f;
#pragma unroll
      for (int c = 0; c < 10; ++c) {
        float xv = xn[c] / ssum;
        if (xv > 0.f) ent -= xv * logf(xv);
        float d = xv - Xs[cur][i][c];
        dp += d * d;
        Xs[cur ^ 1][i][c] = xv;
      }
      entsum += ent;
    }
#pragma unroll
    for (int m = 1; m < 64; m <<= 1) dp += __shfl_xor(dp, m);
    if (l == 0) dredw[it & 1][w] = dp;
    __syncthreads();
    float s = 0.f;
#pragma unroll
    for (int q = 0; q < 16; ++q) s += dredw[it & 1][q];
    nrm2 = s;
    cur ^= 1;
  }

  // ---- outputs ----
  if (g == 0) out[512 + 256 + i] = entsum * (1.0f / 30.0f);   // unlabeled y_true
  for (int e = tid; e < 256; e += 1024) {
    out[512 + e] = 0.f;            // labeled y_true (entropy of one-hot = 0)
    out[6144 + e] = 1.f;           // mask labeled
    out[6144 + 256 + e] = 0.f;     // mask unlabeled
  }
  for (int e = tid; e < 2560; e += 1024) {
    int rr = e / 10, c = e % 10;
    out[1024 + e] = (labs[rr] == c) ? 1.f : 0.f;   // labeled X (exact one-hot)
    out[1024 + 2560 + e] = Xs[cur][rr][c];         // unlabeled X (latest buffer)
  }
}

extern "C" void kernel_launch(void* const* d_in, const int* in_sizes, int n_in,
                              void* d_out, int out_size, void* d_ws, size_t ws_size,
                              hipStream_t stream) {
  (void)in_sizes; (void)n_in; (void)out_size;

  const float* feat[4]; const float* cw[4]; const float* cbp[4];
  const float* bg[4]; const float* bbp[4]; const float* lw[4]; const float* lbp[4];
  for (int b = 0; b < 4; ++b) {
    int base = b * 7;
    feat[b] = (const float*)d_in[base + 0];
    cw[b]  = (const float*)d_in[base + 1];
    cbp[b] = (const float*)d_in[base + 2];
    bg[b]  = (const float*)d_in[base + 3];
    bbp[b] = (const float*)d_in[base + 4];
    lw[b]  = (const float*)d_in[base + 5];
    lbp[b] = (const float*)d_in[base + 6];
  }
  const float* finw = (const float*)d_in[28];
  const float* finb = (const float*)d_in[29];
  const float* emb  = (const float*)d_in[30];
  const int* labels = (const int*)d_in[31];
  float* out = (float*)d_out;

  // ---- workspace layout (float offsets) ----
  float* wsf = (float*)d_ws;
  unsigned short* xpad = (unsigned short*)wsf;                    // 16.78 MB
  unsigned short* yP   = (unsigned short*)(wsf + 4194304);        // 33.55 MB
  unsigned short* wpk  = (unsigned short*)(wsf + 12582912);       // 6.27 MB
  size_t off = 14149632;
  float* psum = wsf + off; off += 524288;
  float* psq  = wsf + off; off += 524288;
  float* pp   = wsf + off; off += 524288;
  float* scale = wsf + off; off += 512;
  float* shift = wsf + off; off += 512;
  float* pooled = wsf + off; off += 491520;
  float* oc = wsf + off; off += 262144;
  float* sq = wsf + off; off += 512;
  float* A0 = wsf + off; off += 262144;
  float* Am = wsf + off; off += 262144;
  float* sig = wsf + off; off += 512;
  int* idx7 = (int*)(wsf + off); off += 512;
  float* meanPart = wsf + off; off += 256;
  float* meanA = wsf + off; off += 4;
  size_t yb0_off = off;
  unsigned short* yB0 = (unsigned short*)(wsf + yb0_off);         // 67.1 MB (optional)
  const bool bigB0 = ws_size >= (yb0_off + 16777216) * sizeof(float);

  unsigned short* wpkB[4] = {wpk, wpk + 36864, wpk + 184320, wpk + 774144};

  wpack_all<<<(3133440 + 255) / 256, 256, 0, stream>>>(cw[0], cw[1], cw[2], cw[3], wpk);

  // ===== branch 1: C=128, S=16 (xpad chunked x2) =====
  for (int c = 0; c < 2; ++c) {
    xpack_kernel<128, 16><<<256 * 16, 256, 0, stream>>>(feat[1] + (size_t)c * 8388608, xpad);
    conv_mfma<128, 16, 1, 8, 4, 2, 0><<<dim3(512, 2), 256, 0, stream>>>(
        xpad, wpkB[1], cbp[1], yP + (size_t)c * 8388608, psum, psq, 4096, c * 2048,
        nullptr, nullptr, nullptr, 0);
  }
  stats2_kernel<<<128, 256, 0, stream>>>(psum, psq, bg[1], bbp[1], scale, shift, 4096, 1.f / 131072.f);
  pool_lin<128, 16><<<512, 256, 0, stream>>>(yP, scale, shift, lw[1], lbp[1], oc, 128);

  // ===== branch 2: C=256, S=8 =====
  xpack_kernel<256, 8><<<512 * 8, 256, 0, stream>>>(feat[2], xpad);
  conv_mfma<256, 8, 2, 8, 4, 2, 0><<<dim3(256, 4), 256, 0, stream>>>(
      xpad, wpkB[2], cbp[2], yP, psum, psq, 1024, 0, nullptr, nullptr, nullptr, 0);
  stats2_kernel<<<256, 256, 0, stream>>>(psum, psq, bg[2], bbp[2], scale, shift, 1024, 1.f / 32768.f);
  pool_lin<256, 8><<<512, 256, 0, stream>>>(yP, scale, shift, lw[2], lbp[2], oc, 256);

  // ===== branch 3: C=512, S=4 =====
  xpack_kernel<512, 4><<<512 * 4, 256, 0, stream>>>(feat[3], xpad);
  conv_mfma<512, 4, 8, 4, 4, 2, 0><<<dim3(64, 8), 256, 0, stream>>>(
      xpad, wpkB[3], cbp[3], yP, psum, psq, 256, 0, nullptr, nullptr, nullptr, 0);
  stats2_kernel<<<512, 256, 0, stream>>>(psum, psq, bg[3], bbp[3], scale, shift, 256, 1.f / 8192.f);
  pool_lin<512, 4><<<512, 256, 0, stream>>>(yP, scale, shift, lw[3], lbp[3], oc, 384);

  // ===== branch 0: C=64, S=32 =====
  if (bigB0) {
    for (int c = 0; c < 4; ++c) {
      xpack_kernel<64, 32><<<128 * 32, 256, 0, stream>>>(feat[0] + (size_t)c * 8388608, xpad);
      conv_mfma<64, 32, 1, 8, 4, 4, 0><<<dim3(512, 1), 256, 0, stream>>>(
          xpad, wpkB[0], cbp[0], yB0 + (size_t)c * 8388608, psum, psq, 8192, c * 2048,
          nullptr, nullptr, nullptr, 0);
    }
    stats2_kernel<<<64, 256, 0, stream>>>(psum, psq, bg[0], bbp[0], scale, shift, 8192, 1.f / 524288.f);
    pool_lin<64, 32><<<512, 256, 0, stream>>>(yB0, scale, shift, lw[0], lbp[0], oc, 0);
  } else {
    for (int c = 0; c < 4; ++c) {
      xpack_kernel<64, 32><<<128 * 32, 256, 0, stream>>>(feat[0] + (size_t)c * 8388608, xpad);
      conv_mfma<64, 32, 1, 8, 4, 4, 1><<<dim3(512, 1), 256, 0, stream>>>(
          xpad, wpkB[0], cbp[0], nullptr, psum, psq, 8192, c * 2048, nullptr, nullptr, nullptr, 0);
    }
    stats2_kernel<<<64, 256, 0, stream>>>(psum, psq, bg[0], bbp[0], scale, shift, 8192, 1.f / 524288.f);
    for (int c = 0; c < 4; ++c) {
      xpack_kernel<64, 32><<<128 * 32, 256, 0, stream>>>(feat[0] + (size_t)c * 8388608, xpad);
      conv_mfma<64, 32, 1, 8, 4, 4, 2><<<dim3(512, 1), 256, 0, stream>>>(
          xpad, wpkB[0], cbp[0], nullptr, nullptr, nullptr, 0, 0, scale, shift, pp, c * 131072);
    }
    poolfin_kernel<<<128, 256, 0, stream>>>(pp, pooled);
    lin_kernel<<<256, 256, 0, stream>>>(pooled, lw[0], lbp[0], oc, 64, 0);
  }

  // ===== head + GTG =====
  ypred_kernel<<<128, 256, 0, stream>>>(oc, finw, finb, out);
  sqnorm_kernel<<<128, 256, 0, stream>>>(emb, sq);
  a0_kernel<<<1024, 256, 0, stream>>>(emb, sq, A0);
  seventh_kernel<<<2, 256, 0, stream>>>(A0, idx7);
  sig_kernel<<<128, 256, 0, stream>>>(emb, idx7, sig);
  aexp_kernel<<<256, 256, 0, stream>>>(A0, sig, Am, meanPart);
  meanred_kernel<<<1, 64, 0, stream>>>(meanPart, meanA);
  thresh_kernel<<<256, 256, 0, stream>>>(Am, meanA);

  gtg2<<<1, 1024, 0, stream>>>(Am, labels, out);
}

// Round 11
// 990.279 us; speedup vs baseline: 1.0178x; 1.0073x over previous
//
#include <hip/hip_runtime.h>
#include <hip/hip_bf16.h>
#include <math.h>

static constexpr int kNC = 10;
static constexpr int kNLab = 256;
static constexpr int kMaxIter = 30;

using short8 = __attribute__((ext_vector_type(8))) short;
using f32x4  = __attribute__((ext_vector_type(4))) float;

__device__ __forceinline__ unsigned short f2bf(float f) {
  unsigned int u = __float_as_uint(f);
  u += 0x7FFFu + ((u >> 16) & 1u);   // RNE
  return (unsigned short)(u >> 16);
}
__device__ __forceinline__ float bf2f(unsigned short u) {
  return __uint_as_float(((unsigned int)u) << 16);
}

// ---------------- NCHW fp32 -> NHWC bf16 transpose (per (n,h) row) ----------------
template <int C, int S>
__global__ __launch_bounds__(256) void xpack_kernel(const float* __restrict__ x,
                                                    unsigned short* __restrict__ xp) {
  __shared__ float t[C][S + 1];
  const int n = blockIdx.x / S, h = blockIdx.x % S;
  const float* src = x + (size_t)n * C * S * S;
  for (int e = threadIdx.x; e < C * S; e += 256) {
    int c = e / S, w = e % S;
    t[c][w] = src[((size_t)c * S + h) * S + w];
  }
  __syncthreads();
  unsigned short* dst = xp + ((size_t)(n * S + h) * S) * C;
  for (int e = threadIdx.x; e < C * S; e += 256) {
    int w = e / C, c = e % C;
    dst[(size_t)w * C + c] = f2bf(t[c][w]);
  }
}

// ---------------- all-branch weight pack into MFMA A-fragment order bf16 ----------
// per-branch layout: [tap][cik][co16][lane][8]; co=co16*16+(l&15), ci=cik*32+(l>>4)*8+e
__global__ void wpack_all(const float* __restrict__ w0, const float* __restrict__ w1,
                          const float* __restrict__ w2, const float* __restrict__ w3,
                          unsigned short* __restrict__ wpk) {
  int idx = blockIdx.x * 256 + threadIdx.x;
  if (idx >= 3133440) return;
  const float* w; int C, off;
  if (idx < 36864)        { w = w0; C = 64;  off = 0; }
  else if (idx < 184320)  { w = w1; C = 128; off = 36864; }
  else if (idx < 774144)  { w = w2; C = 256; off = 184320; }
  else                    { w = w3; C = 512; off = 774144; }
  int e = idx - off;
  int CO16T = C / 16, CIK = C / 32;
  int e8 = e & 7, l = (e >> 3) & 63;
  int rest = e >> 9;
  int co16 = rest % CO16T;
  int rest2 = rest / CO16T;
  int cik = rest2 % CIK, tap = rest2 / CIK;
  int co = co16 * 16 + (l & 15);
  int ci = cik * 32 + (l >> 4) * 8 + e8;
  wpk[idx] = f2bf(w[((size_t)co * C + ci) * 9 + tap]);
}

// ---------------- MFMA implicit-GEMM 3x3 SAME conv ----------------
// block: WV waves; px-tile PXB = NI*NR*S; per-wave BF 16-px fragments; 64 co per block.
// MODE 0: store y(NHWC bf16)+stats partials; 1: stats only; 2: fused BN+relu+pool partials
template <int C, int S, int NI, int NR, int WV, int BF, int MODE>
__global__ __launch_bounds__(WV * 64)
void conv_mfma(const unsigned short* __restrict__ xp, const unsigned short* __restrict__ wpk,
               const float* __restrict__ bias, unsigned short* __restrict__ y,
               float* __restrict__ psum, float* __restrict__ psq, int npart, int partBase,
               const float* __restrict__ scale, const float* __restrict__ shift,
               float* __restrict__ pp, int pxGlobalBase) {
  constexpr int SS = S * S;
  constexpr int PXB = NI * NR * S;
  constexpr int TPB = WV * 64;
  constexpr int HR = NR + 2, HC = S + 2;
  constexpr int CIK = C / 32, CO16T = C / 16;
  constexpr int UNITS = NI * HR * HC * 4;
  constexpr int NU = (UNITS + TPB - 1) / TPB;
  static_assert(WV * BF * 16 == PXB, "wave px mismatch");
  static_assert(MODE != 2 || BF == 4, "MODE2 assumes 64px/wave");
  __shared__ __align__(16) char xs[NI * HR * HC * 80];

  const int tid = threadIdx.x;
  const int wv = tid >> 6, l = tid & 63, l15 = l & 15, l4 = l >> 4;
  const int coblk = blockIdx.y;
  const int co_base = coblk * 64;
  const int pxb = blockIdx.x * PXB;
  const int n_t = pxb / SS;
  const int r0 = (pxb % SS) / S;

  int pxoff[BF];
#pragma unroll
  for (int bf = 0; bf < BF; ++bf) {
    int pxloc = wv * (BF * 16) + bf * 16 + l15;
    int ii = pxloc / (NR * S);
    int rr = (pxloc % (NR * S)) / S;
    int cc = pxloc % S;
    pxoff[bf] = ((ii * HR + rr) * HC + cc) * 80 + l4 * 16;
  }

  f32x4 acc[4][BF];
#pragma unroll
  for (int a = 0; a < 4; ++a)
#pragma unroll
    for (int b = 0; b < BF; ++b) acc[a][b] = (f32x4){0.f, 0.f, 0.f, 0.f};

  uint4 vreg[NU];
  auto loadU = [&](int cik) {
#pragma unroll
    for (int k = 0; k < NU; ++k) {
      int u = tid + k * TPB;
      uint4 v = {0u, 0u, 0u, 0u};
      if (u < UNITS) {
        int k16 = u & 3;
        int t = u >> 2;
        int hc = t % HC;
        int t2 = t / HC;
        int hr = t2 % HR;
        int ii = t2 / HR;
        int row = r0 + hr - 1, col = hc - 1;
        if (row >= 0 && row < S && col >= 0 && col < S)
          v = *(const uint4*)(xp + ((size_t)((n_t + ii) * S + row) * S + col) * C + cik * 32 + k16 * 8);
      }
      vreg[k] = v;
    }
  };

  loadU(0);
  for (int cik = 0; cik < CIK; ++cik) {
    __syncthreads();     // previous readers done
#pragma unroll
    for (int k = 0; k < NU; ++k) {
      int u = tid + k * TPB;
      if (u < UNITS) *(uint4*)(xs + (u >> 2) * 80 + (u & 3) * 16) = vreg[k];
    }
    __syncthreads();
    if (cik + 1 < CIK) loadU(cik + 1);   // in flight during MFMA phase
#pragma unroll
    for (int tap = 0; tap < 9; ++tap) {
      const int tapoff = ((tap / 3) * HC + (tap % 3)) * 80;
      short8 wf[4], xf[BF];
#pragma unroll
      for (int af = 0; af < 4; ++af)
        wf[af] = *(const short8*)(wpk + ((size_t)((tap * CIK + cik) * CO16T + coblk * 4 + af) * 64 + l) * 8);
#pragma unroll
      for (int bf = 0; bf < BF; ++bf)
        xf[bf] = *(const short8*)(xs + pxoff[bf] + tapoff);
#pragma unroll
      for (int af = 0; af < 4; ++af)
#pragma unroll
        for (int bf = 0; bf < BF; ++bf)
          acc[af][bf] = __builtin_amdgcn_mfma_f32_16x16x32_bf16(wf[af], xf[bf], acc[af][bf], 0, 0, 0);
    }
  }

  // ---------------- epilogue ----------------
#pragma unroll
  for (int af = 0; af < 4; ++af) {
    const int co0 = co_base + af * 16 + l4 * 4;
    float4 bv = *(const float4*)(bias + co0);
    float s[4] = {0.f, 0.f, 0.f, 0.f}, q[4] = {0.f, 0.f, 0.f, 0.f};
    float4 sc4, sh4;
    if (MODE == 2) {
      sc4 = *(const float4*)(scale + co0);
      sh4 = *(const float4*)(shift + co0);
    }
#pragma unroll
    for (int bf = 0; bf < BF; ++bf) {
      float o[4];
#pragma unroll
      for (int r = 0; r < 4; ++r) o[r] = acc[af][bf][r] + ((const float*)&bv)[r];
      if (MODE == 0) {
        ushort4 pk;
        pk.x = f2bf(o[0]); pk.y = f2bf(o[1]); pk.z = f2bf(o[2]); pk.w = f2bf(o[3]);
        size_t px = (size_t)(pxb + wv * (BF * 16) + bf * 16 + l15);
        *(ushort4*)(y + px * C + co0) = pk;
      }
      if (MODE == 2) {
#pragma unroll
        for (int r = 0; r < 4; ++r)
          s[r] += fmaxf(fmaf(((const float*)&sc4)[r], o[r], ((const float*)&sh4)[r]), 0.f);
      } else {
#pragma unroll
        for (int r = 0; r < 4; ++r) { s[r] += o[r]; q[r] += o[r] * o[r]; }
      }
    }
#pragma unroll
    for (int m = 1; m < 16; m <<= 1) {
#pragma unroll
      for (int r = 0; r < 4; ++r) {
        s[r] += __shfl_xor(s[r], m);
        if (MODE != 2) q[r] += __shfl_xor(q[r], m);
      }
    }
    if (l15 == 0) {
      if (MODE == 2) {
        int n = (pxGlobalBase + pxb) / SS;
        int qw = ((pxGlobalBase + pxb) % SS) / 64 + wv;
#pragma unroll
        for (int r = 0; r < 4; ++r)
          pp[((size_t)(n * C + co0 + r)) * 16 + qw] = s[r];
      } else {
        int part = partBase + blockIdx.x * WV + wv;
#pragma unroll
        for (int r = 0; r < 4; ++r) {
          psum[(size_t)(co0 + r) * npart + part] = s[r];
          psq[(size_t)(co0 + r) * npart + part] = q[r];
        }
      }
    }
  }
}

// ---------------- BN stats finalize (deterministic tree) ----------------
__global__ __launch_bounds__(256)
void stats2_kernel(const float* __restrict__ psum, const float* __restrict__ psq,
                   const float* __restrict__ g, const float* __restrict__ bb,
                   float* __restrict__ scale, float* __restrict__ shift,
                   int npart, float invN) {
  int c = blockIdx.x;
  __shared__ float rs[256], rq[256];
  float s = 0.f, q = 0.f;
  for (int p = threadIdx.x; p < npart; p += 256) {
    s += psum[(size_t)c * npart + p];
    q += psq[(size_t)c * npart + p];
  }
  rs[threadIdx.x] = s; rq[threadIdx.x] = q;
  __syncthreads();
  for (int st = 128; st; st >>= 1) {
    if (threadIdx.x < st) { rs[threadIdx.x] += rs[threadIdx.x + st]; rq[threadIdx.x] += rq[threadIdx.x + st]; }
    __syncthreads();
  }
  if (threadIdx.x == 0) {
    float m = rs[0] * invN;
    float v = rq[0] * invN - m * m;
    float sc = g[c] / sqrtf(v + 1e-5f);
    scale[c] = sc;
    shift[c] = bb[c] - m * sc;
  }
}

// ---------------- fused relu(bn(y NHWC)) spatial mean + linear -> oc ----------------
template <int C, int S>
__global__ __launch_bounds__(256)
void pool_lin(const unsigned short* __restrict__ y, const float* __restrict__ scale,
              const float* __restrict__ shift, const float* __restrict__ lw,
              const float* __restrict__ lb, float* __restrict__ oc, int brOff) {
  constexpr int SS = S * S;
  int n = blockIdx.x;
  const unsigned short* yr = y + (size_t)n * SS * C;
  __shared__ float pl[C];
  if (C >= 256) {
    for (int co = threadIdx.x; co < C; co += 256) {
      float sc = scale[co], sh = shift[co], s = 0.f;
      for (int p = 0; p < SS; ++p) s += fmaxf(fmaf(sc, bf2f(yr[(size_t)p * C + co]), sh), 0.f);
      pl[co] = s * (1.f / SS);
    }
  } else {
    constexpr int G = 256 / C;
    int co = threadIdx.x % C;
    int sl = threadIdx.x / C;
    float sc = scale[co], sh = shift[co], s = 0.f;
    for (int p = sl; p < SS; p += G) s += fmaxf(fmaf(sc, bf2f(yr[(size_t)p * C + co]), sh), 0.f);
    __shared__ float red[256];
    red[threadIdx.x] = s;
    __syncthreads();
    if (threadIdx.x < C) {
      float t = 0.f;
      for (int gg = 0; gg < G; ++gg) t += red[gg * C + co];
      pl[co] = t * (1.f / SS);
    }
  }
  __syncthreads();
  if (threadIdx.x < 128) {
    int j = threadIdx.x;
    const float* wr = lw + (size_t)j * C;
    float s = 0.f;
    for (int t = 0; t < C; ++t) s = fmaf(pl[t], wr[t], s);
    s += lb[j];
    oc[n * 512 + brOff + j] = fmaxf(s, 0.f);
  }
}

// ---------------- branch-0 fallback fused-pool finalize ----------------
__global__ void poolfin_kernel(const float* __restrict__ pp, float* __restrict__ pooled) {
  int i = blockIdx.x * 256 + threadIdx.x;
  if (i >= 512 * 64) return;
  float s = 0.f;
  for (int qn = 0; qn < 16; ++qn) s += pp[(size_t)i * 16 + qn];
  pooled[i] = s * (1.f / 1024.f);
}

// ---------------- relu(pooled @ lw.T + lb) -> oc[n][512] at brOff (fallback) -------
__global__ void lin_kernel(const float* __restrict__ pooled, const float* __restrict__ lw,
                           const float* __restrict__ lb, float* __restrict__ oc,
                           int C, int brOff) {
  int idx = blockIdx.x * 256 + threadIdx.x;
  if (idx >= 512 * 128) return;
  int j = idx & 127, n = idx >> 7;
  const float4* pr = (const float4*)(pooled + (size_t)n * C);
  const float4* wr = (const float4*)(lw + (size_t)j * C);
  float s = 0.f;
  for (int t = 0; t < C / 4; ++t) {
    float4 a = pr[t], b = wr[t];
    s += a.x * b.x + a.y * b.y + a.z * b.z + a.w * b.w;
  }
  s += lb[j];
  oc[n * 512 + brOff + j] = fmaxf(s, 0.f);
}

__global__ void ypred_kernel(const float* __restrict__ oc, const float* __restrict__ fw,
                             const float* __restrict__ fb, float* __restrict__ out) {
  int wv = threadIdx.x >> 6, l = threadIdx.x & 63;
  int n = blockIdx.x * 4 + wv;
  float s = 0.f;
  for (int k = l; k < 512; k += 64) s += oc[n * 512 + k] * fw[k];
#pragma unroll
  for (int m = 32; m; m >>= 1) s += __shfl_down(s, m);
  if (l == 0) out[n] = s + fb[0];
}

// ---------------- GTG graph build ----------------
__global__ void sqnorm_kernel(const float* __restrict__ E, float* __restrict__ sq) {
  int wv = threadIdx.x >> 6, l = threadIdx.x & 63;
  int n = blockIdx.x * 4 + wv;
  const float* row = E + (size_t)n * 512;
  float s = 0.f;
  for (int k = l; k < 512; k += 64) { float v = row[k]; s += v * v; }
#pragma unroll
  for (int m = 32; m; m >>= 1) s += __shfl_down(s, m);
  if (l == 0) sq[n] = s;
}

__global__ __launch_bounds__(256) void a0_kernel(const float* __restrict__ E,
                                                 const float* __restrict__ sq,
                                                 float* __restrict__ A0) {
  int bi = blockIdx.x / 32, bj = blockIdx.x % 32;
  int ti = threadIdx.x % 16, tj = threadIdx.x / 16;
  __shared__ float Ei[16][68], Ej[16][68];
  float acc = 0.f;
  for (int k0 = 0; k0 < 512; k0 += 64) {
    for (int e = threadIdx.x; e < 1024; e += 256) {
      int rr = e >> 6, cc = e & 63;
      Ei[rr][cc] = E[(size_t)(bi * 16 + rr) * 512 + k0 + cc];
      Ej[rr][cc] = E[(size_t)(bj * 16 + rr) * 512 + k0 + cc];
    }
    __syncthreads();
#pragma unroll 16
    for (int kk = 0; kk < 64; ++kk) acc = fmaf(Ei[tj][kk], Ej[ti][kk], acc);
    __syncthreads();
  }
  int i = bi * 16 + tj, j = bj * 16 + ti;
  float d2 = fmaxf(sq[i] + sq[j] - 2.f * acc, 0.f);
  A0[(size_t)i * 512 + j] = fminf(fmaxf(sqrtf(d2), 0.1f), 1.0f);
}

__global__ void seventh_kernel(const float* __restrict__ A0, int* __restrict__ idx7) {
  int i = blockIdx.x * 256 + threadIdx.x;
  if (i >= 512) return;
  float v[7]; int ix[7];
#pragma unroll
  for (int t = 0; t < 7; ++t) { v[t] = 3.4e38f; ix[t] = 0; }
  const float* row = A0 + (size_t)i * 512;
  for (int j = 0; j < 512; ++j) {
    float a = row[j];
    if (a < v[6]) {
      int pos = 6;
      while (pos > 0 && a < v[pos - 1]) { v[pos] = v[pos - 1]; ix[pos] = ix[pos - 1]; --pos; }
      v[pos] = a; ix[pos] = j;
    }
  }
  idx7[i] = ix[6];
}

__global__ void sig_kernel(const float* __restrict__ E, const int* __restrict__ idx7,
                           float* __restrict__ sig) {
  int wv = threadIdx.x >> 6, l = threadIdx.x & 63;
  int n = blockIdx.x * 4 + wv;
  const float* r1 = E + (size_t)n * 512;
  const float* r2 = E + (size_t)idx7[n] * 512;
  float s = 0.f;
  for (int k = l; k < 512; k += 64) { float d = r1[k] - r2[k]; s += d * d; }
#pragma unroll
  for (int m = 32; m; m >>= 1) s += __shfl_down(s, m);
  if (l == 0) sig[n] = fminf(fmaxf(sqrtf(s), 0.1f), 1.0f);
}

__global__ void aexp_kernel(const float* __restrict__ A0, const float* __restrict__ sig,
                            float* __restrict__ A, float* __restrict__ part) {
  int t = blockIdx.x * 256 + threadIdx.x;
  int base = t * 4;
  int i = base >> 9, j0 = base & 511;
  float si = sig[i];
  float4 a = *(const float4*)(A0 + base);
  float4 o;
  o.x = fminf(fmaxf(expf(-a.x * a.x / (si * sig[j0 + 0])), 0.f), 1.f);
  o.y = fminf(fmaxf(expf(-a.y * a.y / (si * sig[j0 + 1])), 0.f), 1.f);
  o.z = fminf(fmaxf(expf(-a.z * a.z / (si * sig[j0 + 2])), 0.f), 1.f);
  o.w = fminf(fmaxf(expf(-a.w * a.w / (si * sig[j0 + 3])), 0.f), 1.f);
  *(float4*)(A + base) = o;
  float lsum = o.x + o.y + o.z + o.w;
#pragma unroll
  for (int m = 32; m; m >>= 1) lsum += __shfl_down(lsum, m);
  __shared__ float sred[4];
  if ((threadIdx.x & 63) == 0) sred[threadIdx.x >> 6] = lsum;
  __syncthreads();
  if (threadIdx.x == 0) part[blockIdx.x] = sred[0] + sred[1] + sred[2] + sred[3];
}

__global__ void meanred_kernel(const float* __restrict__ part, float* __restrict__ meanA) {
  if (threadIdx.x == 0 && blockIdx.x == 0) {
    float s = 0.f;
    for (int p = 0; p < 256; ++p) s += part[p];
    meanA[0] = s * (1.0f / 262144.0f);
  }
}

__global__ void thresh_kernel(float* __restrict__ A, const float* __restrict__ meanA) {
  int t = blockIdx.x * 256 + threadIdx.x;
  int base = t * 4;
  int i = base >> 9, j0 = base & 511;
  float m = meanA[0];
  float4 v = *(const float4*)(A + base);
  v.x = v.x > m ? 1.f : v.x;
  v.y = v.y > m ? 1.f : v.y;
  v.z = v.z > m ? 1.f : v.z;
  v.w = v.w > m ? 1.f : v.w;
  if (i < kNLab && j0 < kNLab) {
    v.x = 1.f - v.x; v.y = 1.f - v.y; v.z = 1.f - v.z; v.w = 1.f - v.w;
  }
  *(float4*)(A + base) = v;
}

// ---------------- A_uu pack into lane-major coalesced order -----------------------
// Apk[(q*1024 + tid)*4 + k] = A[256 + w*16 + (l&15)][256 + (l>>4)*64 + q*4 + k]
__global__ void apack_kernel(const float* __restrict__ A, float* __restrict__ Apk) {
  int t = blockIdx.x * 256 + threadIdx.x;
  if (t >= 16384) return;
  int q = t >> 10, tid = t & 1023;
  int w = tid >> 6, l = tid & 63;
  int i = w * 16 + (l & 15), g = l >> 4;
  float4 v = *(const float4*)(A + (size_t)(256 + i) * 512 + 256 + g * 64 + q * 4);
  *(float4*)(Apk + (size_t)t * 4) = v;
}

// ---------------- replicator: SINGLE block, registers forced, skewed LDS ----------
// wave w owns rows i = w*16 + (l&15); j-slice g = l>>4 covers 64 cols.
// amdgpu_waves_per_eu(4,4): exactly-4 waves/EU target -> 128 VGPR cap -> areg fits.
// asm keep-alives forbid rematerialization of the A loads into the loop.
// X LDS layout skewed: row j at float-offset (j>>6)*772 + (j&63)*12 (group bases
// 3088 B apart -> bank offset 4g -> x0/x1/x2 reads conflict-free across g-groups).
__global__ __launch_bounds__(1024) __attribute__((amdgpu_waves_per_eu(4, 4)))
void gtg3(const float* __restrict__ Apk, const float* __restrict__ A,
          const int* __restrict__ labels, float* __restrict__ out) {
  const int tid = threadIdx.x;
  const int w = tid >> 6, l = tid & 63;
  const int r = l & 15, g = l >> 4;
  const int i = w * 16 + r;                 // unlabeled row 0..255 (global 256+i)
  __shared__ __align__(16) float Xs[2][3088];   // 2 × 4 groups × (64 rows × 12 + 4 pad)
  __shared__ float dredw[2][16];
  __shared__ int labs[256];

  if (tid < 256) labs[tid] = labels[tid];
  for (int e = tid; e < 3088; e += 1024) {
    int o = e % 772;
    Xs[0][e] = (o < 768 && (o % 12) < 10) ? 0.1f : 0.f;
  }
  __syncthreads();

  // A_uu slice -> registers (coalesced loads from Apk)
  float areg[64];
#pragma unroll
  for (int q = 0; q < 16; ++q) {
    float4 v = *(const float4*)(Apk + ((size_t)q * 1024 + tid) * 4);
    areg[q * 4 + 0] = v.x; areg[q * 4 + 1] = v.y;
    areg[q * 4 + 2] = v.z; areg[q * 4 + 3] = v.w;
  }
#pragma unroll
  for (int k = 0; k < 64; ++k) asm volatile("" : "+v"(areg[k]));

  // labeled-column constant lp[10]
  const float* Arl = A + (size_t)(256 + i) * 512 + g * 64;
  float lp[10];
#pragma unroll
  for (int c = 0; c < 10; ++c) lp[c] = 0.f;
#pragma unroll
  for (int q = 0; q < 16; ++q) {
    float4 v = *(const float4*)(Arl + q * 4);
    float av[4] = {v.x, v.y, v.z, v.w};
#pragma unroll
    for (int k = 0; k < 4; ++k) {
      int lab = labs[g * 64 + q * 4 + k];
#pragma unroll
      for (int c = 0; c < 10; ++c) lp[c] += (lab == c) ? av[k] : 0.f;
    }
  }
#pragma unroll
  for (int c = 0; c < 10; ++c) asm volatile("" : "+v"(lp[c]));

  const int irow = (i >> 6) * 772 + (i & 63) * 12;   // this thread's row offset

  float entsum = 0.f;
  float nrm2 = 1e30f;
  int cur = 0;
  for (int it = 0; it < kMaxIter; ++it) {
    if (it > 0 && sqrtf(nrm2) <= 0.001f) break;
    const float* Xc = &Xs[cur][0];
    float ax[10];
#pragma unroll
    for (int c = 0; c < 10; ++c) ax[c] = lp[c];
#pragma unroll
    for (int jj = 0; jj < 64; ++jj) {
      const float* xr = Xc + g * 772 + jj * 12;
      float4 x0 = *(const float4*)(xr);
      float4 x1 = *(const float4*)(xr + 4);
      float2 x2 = *(const float2*)(xr + 8);
      float a = areg[jj];
      ax[0] = fmaf(a, x0.x, ax[0]); ax[1] = fmaf(a, x0.y, ax[1]);
      ax[2] = fmaf(a, x0.z, ax[2]); ax[3] = fmaf(a, x0.w, ax[3]);
      ax[4] = fmaf(a, x1.x, ax[4]); ax[5] = fmaf(a, x1.y, ax[5]);
      ax[6] = fmaf(a, x1.z, ax[6]); ax[7] = fmaf(a, x1.w, ax[7]);
      ax[8] = fmaf(a, x2.x, ax[8]); ax[9] = fmaf(a, x2.y, ax[9]);
    }
    // combine the 4 j-slices across the wave
#pragma unroll
    for (int c = 0; c < 10; ++c) {
      ax[c] += __shfl_xor(ax[c], 16);
      ax[c] += __shfl_xor(ax[c], 32);
    }
    float dp = 0.f;
    if (g == 0) {                      // lanes 0..15 renorm their row
      const float* xo = Xc + irow;
      float* xn_p = &Xs[cur ^ 1][irow];
      float xn[10], ssum = 0.f;
#pragma unroll
      for (int c = 0; c < 10; ++c) { xn[c] = xo[c] * ax[c]; ssum += xn[c]; }
      float ent = 0.f;
#pragma unroll
      for (int c = 0; c < 10; ++c) {
        float xv = xn[c] / ssum;
        if (xv > 0.f) ent -= xv * logf(xv);
        float d = xv - xo[c];
        dp += d * d;
        xn_p[c] = xv;
      }
      entsum += ent;
    }
#pragma unroll
    for (int m = 1; m < 64; m <<= 1) dp += __shfl_xor(dp, m);
    if (l == 0) dredw[it & 1][w] = dp;
    __syncthreads();
    float s = 0.f;
#pragma unroll
    for (int q = 0; q < 16; ++q) s += dredw[it & 1][q];
    nrm2 = s;
    cur ^= 1;
  }

  // ---- outputs ----
  if (g == 0) out[512 + 256 + i] = entsum * (1.0f / 30.0f);   // unlabeled y_true
  for (int e = tid; e < 256; e += 1024) {
    out[512 + e] = 0.f;            // labeled y_true (entropy of one-hot = 0)
    out[6144 + e] = 1.f;           // mask labeled
    out[6144 + 256 + e] = 0.f;     // mask unlabeled
  }
  for (int e = tid; e < 2560; e += 1024) {
    int rr = e / 10, c = e % 10;
    out[1024 + e] = (labs[rr] == c) ? 1.f : 0.f;              // labeled X (one-hot)
    out[1024 + 2560 + e] = Xs[cur][(rr >> 6) * 772 + (rr & 63) * 12 + c];  // unlabeled X
  }
}

extern "C" void kernel_launch(void* const* d_in, const int* in_sizes, int n_in,
                              void* d_out, int out_size, void* d_ws, size_t ws_size,
                              hipStream_t stream) {
  (void)in_sizes; (void)n_in; (void)out_size;

  const float* feat[4]; const float* cw[4]; const float* cbp[4];
  const float* bg[4]; const float* bbp[4]; const float* lw[4]; const float* lbp[4];
  for (int b = 0; b < 4; ++b) {
    int base = b * 7;
    feat[b] = (const float*)d_in[base + 0];
    cw[b]  = (const float*)d_in[base + 1];
    cbp[b] = (const float*)d_in[base + 2];
    bg[b]  = (const float*)d_in[base + 3];
    bbp[b] = (const float*)d_in[base + 4];
    lw[b]  = (const float*)d_in[base + 5];
    lbp[b] = (const float*)d_in[base + 6];
  }
  const float* finw = (const float*)d_in[28];
  const float* finb = (const float*)d_in[29];
  const float* emb  = (const float*)d_in[30];
  const int* labels = (const int*)d_in[31];
  float* out = (float*)d_out;

  // ---- workspace layout (float offsets) ----
  float* wsf = (float*)d_ws;
  unsigned short* xpad = (unsigned short*)wsf;                    // 16.78 MB
  unsigned short* yP   = (unsigned short*)(wsf + 4194304);        // 33.55 MB
  unsigned short* wpk  = (unsigned short*)(wsf + 12582912);       // 6.27 MB
  size_t off = 14149632;
  float* psum = wsf + off; off += 524288;
  float* psq  = wsf + off; off += 524288;
  float* pp   = wsf + off; off += 524288;
  float* scale = wsf + off; off += 512;
  float* shift = wsf + off; off += 512;
  float* pooled = wsf + off; off += 491520;
  float* oc = wsf + off; off += 262144;
  float* sq = wsf + off; off += 512;
  float* A0 = wsf + off; off += 262144;
  float* Am = wsf + off; off += 262144;
  float* sig = wsf + off; off += 512;
  int* idx7 = (int*)(wsf + off); off += 512;
  float* meanPart = wsf + off; off += 256;
  float* meanA = wsf + off; off += 4;
  float* Apk = wsf + off; off += 65536;                           // 256 KB A_uu pack
  size_t yb0_off = off;
  unsigned short* yB0 = (unsigned short*)(wsf + yb0_off);         // 67.1 MB (optional)
  const bool bigB0 = ws_size >= (yb0_off + 16777216) * sizeof(float);

  unsigned short* wpkB[4] = {wpk, wpk + 36864, wpk + 184320, wpk + 774144};

  wpack_all<<<(3133440 + 255) / 256, 256, 0, stream>>>(cw[0], cw[1], cw[2], cw[3], wpk);

  // ===== branch 1: C=128, S=16 (xpad chunked x2) =====
  for (int c = 0; c < 2; ++c) {
    xpack_kernel<128, 16><<<256 * 16, 256, 0, stream>>>(feat[1] + (size_t)c * 8388608, xpad);
    conv_mfma<128, 16, 1, 8, 4, 2, 0><<<dim3(512, 2), 256, 0, stream>>>(
        xpad, wpkB[1], cbp[1], yP + (size_t)c * 8388608, psum, psq, 4096, c * 2048,
        nullptr, nullptr, nullptr, 0);
  }
  stats2_kernel<<<128, 256, 0, stream>>>(psum, psq, bg[1], bbp[1], scale, shift, 4096, 1.f / 131072.f);
  pool_lin<128, 16><<<512, 256, 0, stream>>>(yP, scale, shift, lw[1], lbp[1], oc, 128);

  // ===== branch 2: C=256, S=8 =====
  xpack_kernel<256, 8><<<512 * 8, 256, 0, stream>>>(feat[2], xpad);
  conv_mfma<256, 8, 2, 8, 4, 2, 0><<<dim3(256, 4), 256, 0, stream>>>(
      xpad, wpkB[2], cbp[2], yP, psum, psq, 1024, 0, nullptr, nullptr, nullptr, 0);
  stats2_kernel<<<256, 256, 0, stream>>>(psum, psq, bg[2], bbp[2], scale, shift, 1024, 1.f / 32768.f);
  pool_lin<256, 8><<<512, 256, 0, stream>>>(yP, scale, shift, lw[2], lbp[2], oc, 256);

  // ===== branch 3: C=512, S=4 =====
  xpack_kernel<512, 4><<<512 * 4, 256, 0, stream>>>(feat[3], xpad);
  conv_mfma<512, 4, 8, 4, 4, 2, 0><<<dim3(64, 8), 256, 0, stream>>>(
      xpad, wpkB[3], cbp[3], yP, psum, psq, 256, 0, nullptr, nullptr, nullptr, 0);
  stats2_kernel<<<512, 256, 0, stream>>>(psum, psq, bg[3], bbp[3], scale, shift, 256, 1.f / 8192.f);
  pool_lin<512, 4><<<512, 256, 0, stream>>>(yP, scale, shift, lw[3], lbp[3], oc, 384);

  // ===== branch 0: C=64, S=32 =====
  if (bigB0) {
    for (int c = 0; c < 4; ++c) {
      xpack_kernel<64, 32><<<128 * 32, 256, 0, stream>>>(feat[0] + (size_t)c * 8388608, xpad);
      conv_mfma<64, 32, 1, 8, 4, 4, 0><<<dim3(512, 1), 256, 0, stream>>>(
          xpad, wpkB[0], cbp[0], yB0 + (size_t)c * 8388608, psum, psq, 8192, c * 2048,
          nullptr, nullptr, nullptr, 0);
    }
    stats2_kernel<<<64, 256, 0, stream>>>(psum, psq, bg[0], bbp[0], scale, shift, 8192, 1.f / 524288.f);
    pool_lin<64, 32><<<512, 256, 0, stream>>>(yB0, scale, shift, lw[0], lbp[0], oc, 0);
  } else {
    for (int c = 0; c < 4; ++c) {
      xpack_kernel<64, 32><<<128 * 32, 256, 0, stream>>>(feat[0] + (size_t)c * 8388608, xpad);
      conv_mfma<64, 32, 1, 8, 4, 4, 1><<<dim3(512, 1), 256, 0, stream>>>(
          xpad, wpkB[0], cbp[0], nullptr, psum, psq, 8192, c * 2048, nullptr, nullptr, nullptr, 0);
    }
    stats2_kernel<<<64, 256, 0, stream>>>(psum, psq, bg[0], bbp[0], scale, shift, 8192, 1.f / 524288.f);
    for (int c = 0; c < 4; ++c) {
      xpack_kernel<64, 32><<<128 * 32, 256, 0, stream>>>(feat[0] + (size_t)c * 8388608, xpad);
      conv_mfma<64, 32, 1, 8, 4, 4, 2><<<dim3(512, 1), 256, 0, stream>>>(
          xpad, wpkB[0], cbp[0], nullptr, nullptr, nullptr, 0, 0, scale, shift, pp, c * 131072);
    }
    poolfin_kernel<<<128, 256, 0, stream>>>(pp, pooled);
    lin_kernel<<<256, 256, 0, stream>>>(pooled, lw[0], lbp[0], oc, 64, 0);
  }

  // ===== head + GTG =====
  ypred_kernel<<<128, 256, 0, stream>>>(oc, finw, finb, out);
  sqnorm_kernel<<<128, 256, 0, stream>>>(emb, sq);
  a0_kernel<<<1024, 256, 0, stream>>>(emb, sq, A0);
  seventh_kernel<<<2, 256, 0, stream>>>(A0, idx7);
  sig_kernel<<<128, 256, 0, stream>>>(emb, idx7, sig);
  aexp_kernel<<<256, 256, 0, stream>>>(A0, sig, Am, meanPart);
  meanred_kernel<<<1, 64, 0, stream>>>(meanPart, meanA);
  thresh_kernel<<<256, 256, 0, stream>>>(Am, meanA);

  apack_kernel<<<64, 256, 0, stream>>>(Am, Apk);
  gtg3<<<1, 1024, 0, stream>>>(Apk, Am, labels, out);
}